// Round 5
// baseline (3375.114 us; speedup 1.0000x reference)
//
#include <hip/hip_runtime.h>

#define NN 1048576   // nodes (= 2^20, src fits 20 bits)
#define NE 8388608   // edges
#define NG 32768     // graphs
#define DD 9         // emb dim
#define SH 16        // hbuf row stride (64B line-aligned: random-gather table)
#define SX 12        // X row stride (48B, sequential access only)
#define HH 18        // hidden
#define BN_EPS 1e-5f

#define NPB 512      // nodes per bucket
#define NB  2048     // buckets

// stats buffer offsets (floats)
#define SUM1    0
#define SQ1     18
#define SUM2    36
#define SQ2     45
#define VSUM1   108
#define VSQ1    126
#define VSUM2   144
#define VSQ2    153
#define STATS_FLOATS 256

__device__ __forceinline__ float waveReduce(float v) {
#pragma unroll
  for (int off = 32; off > 0; off >>= 1) v += __shfl_down(v, off, 64);
  return v;
}

// ---------------- binning (once per launch) ----------------

__global__ void k_count(const int* __restrict__ ei, int* __restrict__ bucket_count) {
  __shared__ int hist[NB];
  for (int i = threadIdx.x; i < NB; i += 256) hist[i] = 0;
  __syncthreads();
  const int CH = NE / 2048;
  int base = blockIdx.x * CH;
  for (int i = threadIdx.x; i < CH; i += 256)
    atomicAdd(&hist[ei[NE + base + i] >> 9], 1);
  __syncthreads();
  for (int i = threadIdx.x; i < NB; i += 256)
    if (hist[i]) atomicAdd(&bucket_count[i], hist[i]);
}

// exclusive scan of NB=2048 counts with 256 threads (8 buckets/thread)
__global__ void k_scan(const int* __restrict__ bucket_count, int* __restrict__ bucket_base,
                       int* __restrict__ bucket_cursor) {
  __shared__ int tsum[256];
  int tid = threadIdx.x;
  int c[8];
  int run = 0;
#pragma unroll
  for (int k = 0; k < 8; ++k) { c[k] = bucket_count[tid * 8 + k]; run += c[k]; }
  tsum[tid] = run;
  __syncthreads();
  for (int off = 1; off < 256; off <<= 1) {
    int v = (tid >= off) ? tsum[tid - off] : 0;
    __syncthreads();
    tsum[tid] += v;
    __syncthreads();
  }
  int excl = tsum[tid] - run;
#pragma unroll
  for (int k = 0; k < 8; ++k) {
    bucket_base[tid * 8 + k] = excl;
    bucket_cursor[tid * 8 + k] = excl;
    excl += c[k];
  }
  if (tid == 255) bucket_base[NB] = tsum[255];
}

// record = src | (dst_local<<20) | (attr<<29)   (attrs in {0,1}, 3 bits)
__global__ void k_scatter(const int* __restrict__ ei, const int* __restrict__ ea,
                          int* __restrict__ bucket_cursor, unsigned* __restrict__ binned) {
  __shared__ int hist[NB];
  __shared__ int lbase[NB];
  for (int i = threadIdx.x; i < NB; i += 256) hist[i] = 0;
  __syncthreads();
  const int CH = NE / 512;
  int base = blockIdx.x * CH;
  for (int i = threadIdx.x; i < CH; i += 256)
    atomicAdd(&hist[ei[NE + base + i] >> 9], 1);
  __syncthreads();
  for (int i = threadIdx.x; i < NB; i += 256) {
    int c = hist[i];
    lbase[i] = c ? atomicAdd(&bucket_cursor[i], c) : 0;
    hist[i] = 0;
  }
  __syncthreads();
  for (int i = threadIdx.x; i < CH; i += 256) {
    int e = base + i;
    int s = ei[e];
    int d = ei[NE + e];
    unsigned at = (unsigned)((ea[(size_t)e * 3 + 0] & 1) |
                             ((ea[(size_t)e * 3 + 1] & 1) << 1) |
                             ((ea[(size_t)e * 3 + 2] & 1) << 2));
    int b = d >> 9;
    int pos = lbase[b] + atomicAdd(&hist[b], 1);
    binned[pos] = (unsigned)s | ((unsigned)(d & (NPB - 1)) << 20) | (at << 29);
  }
}

// ---------------- per-layer kernels ----------------

// h_in(0)[n] = sum_f atom_emb[f, x[n,f], :]; vnsum0 = segsum(h_in0, batch)
__global__ void k_atom(const float* __restrict__ atom_emb, const int* __restrict__ x,
                       const int* __restrict__ batch, float* __restrict__ h,
                       float* __restrict__ vnsum) {
  int n = blockIdx.x * 256 + threadIdx.x;
  int xi[9];
#pragma unroll
  for (int f = 0; f < 9; ++f) xi[f] = x[(size_t)n * 9 + f];
  float acc[DD] = {0.f,0.f,0.f,0.f,0.f,0.f,0.f,0.f,0.f};
#pragma unroll
  for (int f = 0; f < 9; ++f) {
    const float* row = atom_emb + ((size_t)f * 119 + xi[f]) * DD;
#pragma unroll
    for (int d = 0; d < DD; ++d) acc[d] += row[d];
  }
  float4* o = (float4*)(h + (size_t)n * SH);
  o[0] = make_float4(acc[0], acc[1], acc[2], acc[3]);
  o[1] = make_float4(acc[4], acc[5], acc[6], acc[7]);
  o[2] = make_float4(acc[8], 0.f, 0.f, 0.f);
  // segmented wave reduction into vnsum (batch sorted)
  int g = batch[n];
  int lane = threadIdx.x & 63;
  float s[DD];
#pragma unroll
  for (int d = 0; d < DD; ++d) s[d] = acc[d];
#pragma unroll
  for (int st = 1; st < 64; st <<= 1) {
    int gu = __shfl_up(g, st, 64);
    bool ok = (lane >= st) && (gu == g);
#pragma unroll
    for (int d = 0; d < DD; ++d) {
      float vu = __shfl_up(s[d], st, 64);
      if (ok) s[d] += vu;
    }
  }
  int gn = __shfl_down(g, 1, 64);
  if ((lane == 63) || (gn != g)) {
#pragma unroll
    for (int d = 0; d < DD; ++d) atomicAdd(&vnsum[(size_t)g * DD + d], s[d]);
  }
}

// One block per bucket: LDS-aggregate relu(h[src]+bond) over dst; write aggr->X
__global__ void __launch_bounds__(256, 6)
k_edge(const float* __restrict__ hbuf, const unsigned* __restrict__ binned,
       const int* __restrict__ bucket_base, const float* __restrict__ bond,
       float* __restrict__ X) {
  __shared__ float slice[NPB * DD];   // 18 KB
  __shared__ float comb[8 * DD];      // precombined bond sums
  int tid = threadIdx.x;
  for (int i = tid; i < NPB * DD; i += 256) slice[i] = 0.f;
  if (tid < 8 * DD) {
    int c = tid / DD, d = tid % DD;
    comb[tid] = bond[(0 * 6 + (c & 1)) * DD + d] +
                bond[(1 * 6 + ((c >> 1) & 1)) * DD + d] +
                bond[(2 * 6 + ((c >> 2) & 1)) * DD + d];
  }
  __syncthreads();

  int b = blockIdx.x;
  int start = bucket_base[b];
  int end = bucket_base[b + 1];
  for (int base = start + tid; base < end; base += 1024) {
    unsigned r[4];
    float4 A[4], B4[4], C4[4];
#pragma unroll
    for (int k = 0; k < 4; ++k) {
      int idx = base + k * 256;
      if (idx < end) {
        unsigned rr = binned[idx];
        r[k] = rr;
        const float4* hs = (const float4*)(hbuf + (size_t)(rr & 0xFFFFFu) * SH);
        A[k] = hs[0]; B4[k] = hs[1]; C4[k] = hs[2];
      }
    }
#pragma unroll
    for (int k = 0; k < 4; ++k) {
      int idx = base + k * 256;
      if (idx < end) {
        float hv[DD] = {A[k].x, A[k].y, A[k].z, A[k].w,
                        B4[k].x, B4[k].y, B4[k].z, B4[k].w, C4[k].x};
        const float* cb = comb + (r[k] >> 29) * DD;
        float* sl = slice + ((r[k] >> 20) & 511u) * DD;
#pragma unroll
        for (int d = 0; d < DD; ++d) {
          float m = hv[d] + cb[d];
          m = m > 0.f ? m : 0.f;
          atomicAdd(&sl[d], m);
        }
      }
    }
  }
  __syncthreads();

  size_t n0 = (size_t)b * NPB;
  for (int node = tid; node < NPB; node += 256) {
    const float* s = slice + node * DD;
    float* xo = X + (n0 + node) * SX;
    ((float4*)xo)[0] = make_float4(s[0], s[1], s[2], s[3]);
    ((float4*)xo)[1] = make_float4(s[4], s[5], s[6], s[7]);
    xo[8] = s[8];
  }
}

// z = (1+eps)*h_in + aggr (in place into X); BN1 stats of (z@W1+b1). 4 nodes/thread.
__global__ void __launch_bounds__(256)
k_partA(float* __restrict__ X, const float* __restrict__ hbuf,
        const float* __restrict__ W1l, const float* __restrict__ b1l,
        const float* __restrict__ epsp, float* __restrict__ stats) {
  __shared__ float sW1[DD * HH], sb1[HH], ssum[HH], ssq[HH];
  int tid = threadIdx.x;
  for (int i = tid; i < DD * HH; i += 256) sW1[i] = W1l[i];
  if (tid < HH) { sb1[tid] = b1l[tid]; ssum[tid] = 0.f; ssq[tid] = 0.f; }
  __syncthreads();
  float eps1 = 1.0f + epsp[0];
  float psum[HH], psq[HH];
#pragma unroll
  for (int j = 0; j < HH; ++j) { psum[j] = 0.f; psq[j] = 0.f; }
  size_t n0 = (size_t)blockIdx.x * 1024;
#pragma unroll
  for (int k = 0; k < 4; ++k) {
    size_t n = n0 + k * 256 + tid;
    const float4* hr = (const float4*)(hbuf + n * SH);
    float4 HA = hr[0], HB = hr[1], HC = hr[2];
    float hi[DD] = {HA.x, HA.y, HA.z, HA.w, HB.x, HB.y, HB.z, HB.w, HC.x};
    float* xr = X + n * SX;
    float4 XA = ((float4*)xr)[0], XB = ((float4*)xr)[1];
    float x8 = xr[8];
    float ag[DD] = {XA.x, XA.y, XA.z, XA.w, XB.x, XB.y, XB.z, XB.w, x8};
    float z[DD];
#pragma unroll
    for (int d = 0; d < DD; ++d) z[d] = eps1 * hi[d] + ag[d];
    ((float4*)xr)[0] = make_float4(z[0], z[1], z[2], z[3]);
    ((float4*)xr)[1] = make_float4(z[4], z[5], z[6], z[7]);
    xr[8] = z[8];
#pragma unroll
    for (int j = 0; j < HH; ++j) {
      float a = sb1[j];
#pragma unroll
      for (int d = 0; d < DD; ++d) a += z[d] * sW1[d * HH + j];
      psum[j] += a;
      psq[j] += a * a;
    }
  }
  int lane0 = ((tid & 63) == 0);
#pragma unroll
  for (int j = 0; j < HH; ++j) {
    float rs = waveReduce(psum[j]);
    float rq = waveReduce(psq[j]);
    if (lane0) { atomicAdd(&ssum[j], rs); atomicAdd(&ssq[j], rq); }
  }
  __syncthreads();
  if (tid < HH) {
    atomicAdd(&stats[SUM1 + tid], ssum[tid]);
    atomicAdd(&stats[SQ1 + tid], ssq[tid]);
  }
}

// in-place X: z2 = relu(bn1(z@W1+b1)) @ W2 + b2;  BN2 stats. bnfin folded in.
__global__ void __launch_bounds__(256)
k_partB(float* __restrict__ X, const float* __restrict__ W1l, const float* __restrict__ b1l,
        const float* __restrict__ g1, const float* __restrict__ be1,
        const float* __restrict__ W2l, const float* __restrict__ b2l,
        float* __restrict__ stats) {
  __shared__ float sW1[DD * HH], sW2[HH * DD], sb1[HH], sb2[DD];
  __shared__ float sc1[HH], sh1[HH], ssum[DD], ssq[DD];
  int tid = threadIdx.x;
  for (int i = tid; i < DD * HH; i += 256) sW1[i] = W1l[i];
  for (int i = tid; i < HH * DD; i += 256) sW2[i] = W2l[i];
  if (tid < HH) {
    float mean = stats[SUM1 + tid] * (1.0f / NN);
    float var = stats[SQ1 + tid] * (1.0f / NN) - mean * mean;
    float sc = g1[tid] * rsqrtf(var + BN_EPS);
    sc1[tid] = sc;
    sh1[tid] = be1[tid] - mean * sc;
    sb1[tid] = b1l[tid];
  }
  if (tid < DD) { sb2[tid] = b2l[tid]; ssum[tid] = 0.f; ssq[tid] = 0.f; }
  __syncthreads();
  size_t n = (size_t)blockIdx.x * 256 + tid;
  float* xr = X + n * SX;
  float4 XA = ((float4*)xr)[0], XB = ((float4*)xr)[1];
  float x8 = xr[8];
  float z[DD] = {XA.x, XA.y, XA.z, XA.w, XB.x, XB.y, XB.z, XB.w, x8};
  float t[HH];
#pragma unroll
  for (int j = 0; j < HH; ++j) {
    float a = sb1[j];
#pragma unroll
    for (int d = 0; d < DD; ++d) a += z[d] * sW1[d * HH + j];
    a = a * sc1[j] + sh1[j];
    t[j] = a > 0.f ? a : 0.f;
  }
  float z2[DD];
  int lane0 = ((tid & 63) == 0);
#pragma unroll
  for (int d = 0; d < DD; ++d) {
    float a = sb2[d];
#pragma unroll
    for (int j = 0; j < HH; ++j) a += t[j] * sW2[j * DD + d];
    z2[d] = a;
    float rs = waveReduce(a);
    float rq = waveReduce(a * a);
    if (lane0) { atomicAdd(&ssum[d], rs); atomicAdd(&ssq[d], rq); }
  }
  ((float4*)xr)[0] = make_float4(z2[0], z2[1], z2[2], z2[3]);
  ((float4*)xr)[1] = make_float4(z2[4], z2[5], z2[6], z2[7]);
  xr[8] = z2[8];
  __syncthreads();
  if (tid < DD) {
    atomicAdd(&stats[SUM2 + tid], ssum[tid]);
    atomicAdd(&stats[SQ2 + tid], ssq[tid]);
  }
}

// h_new = bn2(z2)[relu] + h_in; if vn_next: hbuf = h_new + vn_next[batch]
// (+ optional vnsum segsum); else (last layer) accumulate column sums into out.
__global__ void __launch_bounds__(256)
k_partC(const float* __restrict__ X, float* __restrict__ hbuf,
        const float* __restrict__ stats, const float* __restrict__ g2,
        const float* __restrict__ be2, const int* __restrict__ batch,
        const float* __restrict__ vn_next, float* __restrict__ vnsum_out,
        int do_relu, float* __restrict__ out) {
  __shared__ float sc[DD], sh[DD], ssum[DD];
  int tid = threadIdx.x;
  if (tid < DD) {
    float mean = stats[SUM2 + tid] * (1.0f / NN);
    float var = stats[SQ2 + tid] * (1.0f / NN) - mean * mean;
    float s = g2[tid] * rsqrtf(var + BN_EPS);
    sc[tid] = s;
    sh[tid] = be2[tid] - mean * s;
    ssum[tid] = 0.f;
  }
  __syncthreads();
  size_t n = (size_t)blockIdx.x * 256 + tid;
  const float* xr = X + n * SX;
  float4 XA = ((const float4*)xr)[0], XB = ((const float4*)xr)[1];
  float x8 = xr[8];
  float zv[DD] = {XA.x, XA.y, XA.z, XA.w, XB.x, XB.y, XB.z, XB.w, x8};
  float* hr = hbuf + n * SH;
  float4 HA = ((float4*)hr)[0], HB = ((float4*)hr)[1], HC = ((float4*)hr)[2];
  float hi[DD] = {HA.x, HA.y, HA.z, HA.w, HB.x, HB.y, HB.z, HB.w, HC.x};
  float hv[DD];
#pragma unroll
  for (int d = 0; d < DD; ++d) {
    float z = zv[d] * sc[d] + sh[d];
    if (do_relu) z = z > 0.f ? z : 0.f;
    hv[d] = z + hi[d];
  }
  if (vn_next != nullptr) {
    int g = batch[n];
#pragma unroll
    for (int d = 0; d < DD; ++d) hv[d] += vn_next[(size_t)g * DD + d];
    ((float4*)hr)[0] = make_float4(hv[0], hv[1], hv[2], hv[3]);
    ((float4*)hr)[1] = make_float4(hv[4], hv[5], hv[6], hv[7]);
    hr[8] = hv[8];
    if (vnsum_out != nullptr) {
      int lane = tid & 63;
      float s[DD];
#pragma unroll
      for (int d = 0; d < DD; ++d) s[d] = hv[d];
#pragma unroll
      for (int st = 1; st < 64; st <<= 1) {
        int gu = __shfl_up(g, st, 64);
        bool ok = (lane >= st) && (gu == g);
#pragma unroll
        for (int d = 0; d < DD; ++d) {
          float vu = __shfl_up(s[d], st, 64);
          if (ok) s[d] += vu;
        }
      }
      int gn = __shfl_down(g, 1, 64);
      if ((lane == 63) || (gn != g)) {
#pragma unroll
        for (int d = 0; d < DD; ++d) atomicAdd(&vnsum_out[(size_t)g * DD + d], s[d]);
      }
    }
  } else {
    int lane0 = ((tid & 63) == 0);
#pragma unroll
    for (int d = 0; d < DD; ++d) {
      float r = waveReduce(hv[d]);
      if (lane0) atomicAdd(&ssum[d], r);
    }
    __syncthreads();
    if (tid < DD) atomicAdd(&out[tid], ssum[tid]);
  }
}

// ---------------- virtual-node MLP ----------------

__global__ void k_vnA(const float* __restrict__ vnsum, const float* __restrict__ vn,
                      float* __restrict__ vt1, const float* __restrict__ W1l,
                      const float* __restrict__ b1l, float* __restrict__ stats) {
  __shared__ float sW[DD * HH], sb[HH], ssum[HH], ssq[HH];
  int tid = threadIdx.x;
  for (int i = tid; i < DD * HH; i += 256) sW[i] = W1l[i];
  if (tid < HH) { sb[tid] = b1l[tid]; ssum[tid] = 0.f; ssq[tid] = 0.f; }
  __syncthreads();
  size_t g = (size_t)blockIdx.x * 256 + tid;
  float r[DD];
#pragma unroll
  for (int d = 0; d < DD; ++d) r[d] = vnsum[g * DD + d] + vn[g * DD + d];
  int lane0 = ((tid & 63) == 0);
#pragma unroll
  for (int j = 0; j < HH; ++j) {
    float a = sb[j];
#pragma unroll
    for (int d = 0; d < DD; ++d) a += r[d] * sW[d * HH + j];
    vt1[g * HH + j] = a;
    float rs = waveReduce(a);
    float rq = waveReduce(a * a);
    if (lane0) { atomicAdd(&ssum[j], rs); atomicAdd(&ssq[j], rq); }
  }
  __syncthreads();
  if (tid < HH) {
    atomicAdd(&stats[VSUM1 + tid], ssum[tid]);
    atomicAdd(&stats[VSQ1 + tid], ssq[tid]);
  }
}

__global__ void k_vnB(const float* __restrict__ vt1, float* __restrict__ vt2,
                      const float* __restrict__ W2l, const float* __restrict__ b2l,
                      const float* __restrict__ g1, const float* __restrict__ be1,
                      float* __restrict__ stats) {
  __shared__ float sW2[HH * DD], sb2[DD], sc1[HH], sh1[HH], ssum[DD], ssq[DD];
  int tid = threadIdx.x;
  for (int i = tid; i < HH * DD; i += 256) sW2[i] = W2l[i];
  if (tid < HH) {
    float mean = stats[VSUM1 + tid] * (1.0f / NG);
    float var = stats[VSQ1 + tid] * (1.0f / NG) - mean * mean;
    float sc = g1[tid] * rsqrtf(var + BN_EPS);
    sc1[tid] = sc;
    sh1[tid] = be1[tid] - mean * sc;
  }
  if (tid < DD) { sb2[tid] = b2l[tid]; ssum[tid] = 0.f; ssq[tid] = 0.f; }
  __syncthreads();
  size_t g = (size_t)blockIdx.x * 256 + tid;
  float t[HH];
#pragma unroll
  for (int j = 0; j < HH; ++j) {
    float a = vt1[g * HH + j] * sc1[j] + sh1[j];
    t[j] = a > 0.f ? a : 0.f;
  }
  int lane0 = ((tid & 63) == 0);
#pragma unroll
  for (int d = 0; d < DD; ++d) {
    float a = sb2[d];
#pragma unroll
    for (int j = 0; j < HH; ++j) a += t[j] * sW2[j * DD + d];
    vt2[g * DD + d] = a;
    float rs = waveReduce(a);
    float rq = waveReduce(a * a);
    if (lane0) { atomicAdd(&ssum[d], rs); atomicAdd(&ssq[d], rq); }
  }
  __syncthreads();
  if (tid < DD) {
    atomicAdd(&stats[VSUM2 + tid], ssum[tid]);
    atomicAdd(&stats[VSQ2 + tid], ssq[tid]);
  }
}

__global__ void k_vnC(const float* __restrict__ vt2, float* __restrict__ vn,
                      const float* __restrict__ g2, const float* __restrict__ be2,
                      const float* __restrict__ stats) {
  __shared__ float sc[DD], sh[DD];
  int tid = threadIdx.x;
  if (tid < DD) {
    float mean = stats[VSUM2 + tid] * (1.0f / NG);
    float var = stats[VSQ2 + tid] * (1.0f / NG) - mean * mean;
    float s = g2[tid] * rsqrtf(var + BN_EPS);
    sc[tid] = s;
    sh[tid] = be2[tid] - mean * s;
  }
  __syncthreads();
  size_t g = (size_t)blockIdx.x * 256 + tid;
#pragma unroll
  for (int d = 0; d < DD; ++d) {
    float v = vt2[g * DD + d] * sc[d] + sh[d];
    v = v > 0.f ? v : 0.f;
    vn[g * DD + d] += v;
  }
}

extern "C" void kernel_launch(void* const* d_in, const int* in_sizes, int n_in,
                              void* d_out, int out_size, void* d_ws, size_t ws_size,
                              hipStream_t stream) {
  const float* atom_emb = (const float*)d_in[0];
  const float* bond_emb = (const float*)d_in[1];
  const float* eps_gin  = (const float*)d_in[2];
  const float* W1   = (const float*)d_in[3];
  const float* b1   = (const float*)d_in[4];
  const float* bn1_g = (const float*)d_in[5];
  const float* bn1_b = (const float*)d_in[6];
  const float* W2   = (const float*)d_in[7];
  const float* b2   = (const float*)d_in[8];
  const float* bno_g = (const float*)d_in[9];
  const float* bno_b = (const float*)d_in[10];
  const float* vnW1 = (const float*)d_in[11];
  const float* vnb1 = (const float*)d_in[12];
  const float* vnbn1_g = (const float*)d_in[13];
  const float* vnbn1_b = (const float*)d_in[14];
  const float* vnW2 = (const float*)d_in[15];
  const float* vnb2 = (const float*)d_in[16];
  const float* vnbn2_g = (const float*)d_in[17];
  const float* vnbn2_b = (const float*)d_in[18];
  const int* x          = (const int*)d_in[19];
  const int* edge_index = (const int*)d_in[20];
  const int* edge_attr  = (const int*)d_in[21];
  const int* batch      = (const int*)d_in[22];
  float* out = (float*)d_out;

  // workspace layout (floats) — ~156 MB
  float* hbuf  = (float*)d_ws;                         // NN*SH (64B rows)
  float* X     = hbuf + (size_t)NN * SH;               // NN*SX
  unsigned* binned = (unsigned*)(X + (size_t)NN * SX); // NE uint32
  float* vn    = (float*)(binned + (size_t)NE);        // NG*DD
  float* vnsum = vn + (size_t)NG * DD;                 // NG*DD (vt2 overlays this)
  float* vt2   = vnsum;                                // overlay: vnB writes after vnA read
  float* vt1   = vnsum + (size_t)NG * DD;              // NG*HH
  float* stats = vt1 + (size_t)NG * HH;                // STATS_FLOATS
  int* bucket_count  = (int*)(stats + STATS_FLOATS);   // NB
  int* bucket_base   = bucket_count + NB;              // NB+1
  int* bucket_cursor = bucket_base + NB + 1;           // NB

  // ---- one-time binning ----
  (void)hipMemsetAsync(bucket_count, 0, NB * sizeof(int), stream);
  k_count<<<2048, 256, 0, stream>>>(edge_index, bucket_count);
  k_scan<<<1, 256, 0, stream>>>(bucket_count, bucket_base, bucket_cursor);
  k_scatter<<<512, 256, 0, stream>>>(edge_index, edge_attr, bucket_cursor, binned);

  (void)hipMemsetAsync(vn, 0, (size_t)NG * DD * sizeof(float), stream);
  (void)hipMemsetAsync(vnsum, 0, (size_t)NG * DD * sizeof(float), stream);
  (void)hipMemsetAsync(out, 0, (size_t)DD * sizeof(float), stream);
  k_atom<<<NN / 256, 256, 0, stream>>>(atom_emb, x, batch, hbuf, vnsum);

  for (int l = 0; l < 3; ++l) {
    int has_vn = (l < 2);
    (void)hipMemsetAsync(stats, 0, STATS_FLOATS * sizeof(float), stream);
    if (has_vn) {
      k_vnA<<<NG / 256, 256, 0, stream>>>(vnsum, vn, vt1, vnW1 + (size_t)l * DD * HH,
                                          vnb1 + (size_t)l * HH, stats);
      k_vnB<<<NG / 256, 256, 0, stream>>>(vt1, vt2, vnW2 + (size_t)l * HH * DD,
                                          vnb2 + (size_t)l * DD,
                                          vnbn1_g + (size_t)l * HH, vnbn1_b + (size_t)l * HH,
                                          stats);
      k_vnC<<<NG / 256, 256, 0, stream>>>(vt2, vn, vnbn2_g + (size_t)l * DD,
                                          vnbn2_b + (size_t)l * DD, stats);
    }
    k_edge<<<NB, 256, 0, stream>>>(hbuf, binned, bucket_base,
                                   bond_emb + (size_t)l * 3 * 6 * DD, X);
    k_partA<<<NN / 1024, 256, 0, stream>>>(X, hbuf, W1 + (size_t)l * DD * HH,
                                           b1 + (size_t)l * HH, eps_gin + l, stats);
    k_partB<<<NN / 256, 256, 0, stream>>>(X, W1 + (size_t)l * DD * HH,
                                          b1 + (size_t)l * HH,
                                          bn1_g + (size_t)l * HH, bn1_b + (size_t)l * HH,
                                          W2 + (size_t)l * HH * DD, b2 + (size_t)l * DD,
                                          stats);
    if (l == 0)
      (void)hipMemsetAsync(vnsum, 0, (size_t)NG * DD * sizeof(float), stream);
    k_partC<<<NN / 256, 256, 0, stream>>>(X, hbuf, stats,
                                          bno_g + (size_t)l * DD, bno_b + (size_t)l * DD,
                                          batch,
                                          has_vn ? vn : nullptr,
                                          (l == 0) ? vnsum : nullptr,
                                          has_vn ? 1 : 0,
                                          (l == 2) ? out : nullptr);
  }
}

// Round 7
// 2626.452 us; speedup vs baseline: 1.2850x; 1.2850x over previous
//
#include <hip/hip_runtime.h>

#define NN 1048576   // nodes (= 2^20, src fits 20 bits)
#define NE 8388608   // edges
#define NG 32768     // graphs
#define DD 9         // emb dim
#define SH 16        // hbuf row stride (64B line-aligned: random-gather table)
#define SX 12        // X row stride (48B, sequential access only)
#define HH 18        // hidden
#define BN_EPS 1e-5f

#define NPB 512      // nodes per fine bucket
#define NB  2048     // fine buckets
#define NGRP 64      // coarse dst-groups (32 fine buckets each, 16384 nodes)

// stats buffer offsets (floats)
#define SUM1    0
#define SQ1     18
#define SUM2    36
#define SQ2     45
#define VSUM1   108
#define VSQ1    126
#define VSUM2   144
#define VSQ2    153
#define STATS_FLOATS 256

typedef float fv4 __attribute__((ext_vector_type(4)));

__device__ __forceinline__ float waveReduce(float v) {
#pragma unroll
  for (int off = 32; off > 0; off >>= 1) v += __shfl_down(v, off, 64);
  return v;
}

// ---------------- binning (coalesced two-pass) ----------------

__global__ void k_count(const int* __restrict__ ei, int* __restrict__ bucket_count) {
  __shared__ int hist[NB];
  for (int i = threadIdx.x; i < NB; i += 256) hist[i] = 0;
  __syncthreads();
  const int CH = NE / 2048;
  int base = blockIdx.x * CH;
  for (int i = threadIdx.x; i < CH; i += 256)
    atomicAdd(&hist[ei[NE + base + i] >> 9], 1);
  __syncthreads();
  for (int i = threadIdx.x; i < NB; i += 256)
    if (hist[i]) atomicAdd(&bucket_count[i], hist[i]);
}

// scan 2048 counts -> bucket_base/cursor; group cursors (padded stride 16)
__global__ void k_scan(const int* __restrict__ bucket_count, int* __restrict__ bucket_base,
                       int* __restrict__ bucket_cursor, int* __restrict__ group_cursor) {
  __shared__ int tsum[256];
  int tid = threadIdx.x;
  int c[8];
  int run = 0;
#pragma unroll
  for (int k = 0; k < 8; ++k) { c[k] = bucket_count[tid * 8 + k]; run += c[k]; }
  tsum[tid] = run;
  __syncthreads();
  for (int off = 1; off < 256; off <<= 1) {
    int v = (tid >= off) ? tsum[tid - off] : 0;
    __syncthreads();
    tsum[tid] += v;
    __syncthreads();
  }
  int excl = tsum[tid] - run;
  if ((tid & 3) == 0) group_cursor[(tid >> 2) * 16] = excl;  // base of bucket tid*8 = group boundary
#pragma unroll
  for (int k = 0; k < 8; ++k) {
    bucket_base[tid * 8 + k] = excl;
    bucket_cursor[tid * 8 + k] = excl;
    excl += c[k];
  }
  if (tid == 255) bucket_base[NB] = tsum[255];
}

// pass 1: bin edges into 64 dst-groups; record uint2 {src|attr<<20, dst}; staged flushes
#define P1K 48
__global__ void __launch_bounds__(256)
k_p1(const int* __restrict__ ei, const int* __restrict__ ea,
     int* __restrict__ group_cursor, uint2* __restrict__ coarse) {
  __shared__ uint2 stage[NGRP * P1K];   // 24 KB
  __shared__ int scnt[NGRP], gbase[NGRP];
  int tid = threadIdx.x;
  for (int i = tid; i < NGRP; i += 256) scnt[i] = 0;
  __syncthreads();
  const int CH = NE / 512;   // 16384 per block
  int base = blockIdx.x * CH;
  for (int batch = 0; batch < CH / 1024; ++batch) {
#pragma unroll
    for (int k = 0; k < 4; ++k) {
      int e = base + batch * 1024 + k * 256 + tid;
      int s = ei[e];
      int d = ei[NE + e];
      unsigned at = (unsigned)((ea[(size_t)e * 3 + 0] & 1) |
                               ((ea[(size_t)e * 3 + 1] & 1) << 1) |
                               ((ea[(size_t)e * 3 + 2] & 1) << 2));
      int g = d >> 14;
      uint2 rec = make_uint2((unsigned)s | (at << 20), (unsigned)d);
      int pos = atomicAdd(&scnt[g], 1);
      if (pos < P1K) stage[g * P1K + pos] = rec;
      else coarse[atomicAdd(&group_cursor[g * 16], 1)] = rec;  // rare slow path
    }
    __syncthreads();
    {  // flush: 4 threads per group
      int g = tid >> 2, j = tid & 3;
      int cnt = min(scnt[g], P1K);
      if (j == 0) gbase[g] = cnt ? atomicAdd(&group_cursor[g * 16], cnt) : 0;
      __syncthreads();
      for (int i = j; i < cnt; i += 4) coarse[gbase[g] + i] = stage[g * P1K + i];
    }
    __syncthreads();
    if (tid < NGRP) scnt[tid] = 0;
    __syncthreads();
  }
}

// pass 2: per group -> 32 fine buckets; final 4B record; staged 64B flushes
#define P2K 48
__global__ void __launch_bounds__(256)
k_p2(const uint2* __restrict__ coarse, const int* __restrict__ bucket_base,
     int* __restrict__ bucket_cursor, unsigned* __restrict__ binned) {
  __shared__ unsigned stage[32 * P2K];  // 6 KB
  __shared__ int scnt[32], gbase[32];
  int tid = threadIdx.x;
  int g = blockIdx.x >> 3;          // 8 blocks per group
  int sub = blockIdx.x & 7;
  int s0 = bucket_base[g << 5];
  int s1 = bucket_base[(g + 1) << 5];
  int len = s1 - s0;
  int chunk = (len + 7) >> 3;
  int my0 = s0 + sub * chunk;
  int my1 = min(my0 + chunk, s1);
  if (tid < 32) scnt[tid] = 0;
  __syncthreads();
  for (int b0 = my0; b0 < my1; b0 += 1024) {
#pragma unroll
    for (int k = 0; k < 4; ++k) {
      int i = b0 + k * 256 + tid;
      if (i < my1) {
        uint2 rec = coarse[i];
        unsigned s = rec.x & 0xFFFFFu;
        unsigned at = rec.x >> 20;
        unsigned d = rec.y;
        int bt = (int)((d >> 9) & 31u);
        unsigned out = s | ((d & 511u) << 20) | (at << 29);
        int pos = atomicAdd(&scnt[bt], 1);
        if (pos < P2K) stage[bt * P2K + pos] = out;
        else binned[atomicAdd(&bucket_cursor[(g << 5) | bt], 1)] = out;
      }
    }
    __syncthreads();
    {  // flush: 8 threads per fine bucket
      int bt = tid >> 3, j = tid & 7;
      int cnt = min(scnt[bt], P2K);
      if (j == 0) gbase[bt] = cnt ? atomicAdd(&bucket_cursor[(g << 5) | bt], cnt) : 0;
      __syncthreads();
      for (int i = j; i < cnt; i += 8) binned[gbase[bt] + i] = stage[bt * P2K + i];
    }
    __syncthreads();
    if (tid < 32) scnt[tid] = 0;
    __syncthreads();
  }
}

// ---------------- per-layer kernels ----------------

// h_in(0)[n] = sum_f atom_emb[f, x[n,f], :]; vnsum0 = segsum(h_in0, batch)
__global__ void k_atom(const float* __restrict__ atom_emb, const int* __restrict__ x,
                       const int* __restrict__ batch, float* __restrict__ h,
                       float* __restrict__ vnsum) {
  int n = blockIdx.x * 256 + threadIdx.x;
  int xi[9];
#pragma unroll
  for (int f = 0; f < 9; ++f) xi[f] = x[(size_t)n * 9 + f];
  float acc[DD] = {0.f,0.f,0.f,0.f,0.f,0.f,0.f,0.f,0.f};
#pragma unroll
  for (int f = 0; f < 9; ++f) {
    const float* row = atom_emb + ((size_t)f * 119 + xi[f]) * DD;
#pragma unroll
    for (int d = 0; d < DD; ++d) acc[d] += row[d];
  }
  float4* o = (float4*)(h + (size_t)n * SH);
  o[0] = make_float4(acc[0], acc[1], acc[2], acc[3]);
  o[1] = make_float4(acc[4], acc[5], acc[6], acc[7]);
  o[2] = make_float4(acc[8], 0.f, 0.f, 0.f);
  int g = batch[n];
  int lane = threadIdx.x & 63;
  float s[DD];
#pragma unroll
  for (int d = 0; d < DD; ++d) s[d] = acc[d];
#pragma unroll
  for (int st = 1; st < 64; st <<= 1) {
    int gu = __shfl_up(g, st, 64);
    bool ok = (lane >= st) && (gu == g);
#pragma unroll
    for (int d = 0; d < DD; ++d) {
      float vu = __shfl_up(s[d], st, 64);
      if (ok) s[d] += vu;
    }
  }
  int gn = __shfl_down(g, 1, 64);
  if ((lane == 63) || (gn != g)) {
#pragma unroll
    for (int d = 0; d < DD; ++d) atomicAdd(&vnsum[(size_t)g * DD + d], s[d]);
  }
}

// Fused: LDS-aggregate messages; z = (1+eps)*h_in + aggr -> X; BN1 stats of z@W1+b1
__global__ void __launch_bounds__(256)
k_edgeA(const float* __restrict__ hbuf, const unsigned* __restrict__ binned,
        const int* __restrict__ bucket_base, const float* __restrict__ bond,
        const float* __restrict__ W1l, const float* __restrict__ b1l,
        const float* __restrict__ epsp, float* __restrict__ X,
        float* __restrict__ stats) {
  __shared__ float slice[NPB * DD];   // 18 KB
  __shared__ float comb[8 * DD];
  __shared__ float sW1[DD * HH], sb1[HH], ssum[HH], ssq[HH];
  int tid = threadIdx.x;
  for (int i = tid; i < NPB * DD; i += 256) slice[i] = 0.f;
  for (int i = tid; i < DD * HH; i += 256) sW1[i] = W1l[i];
  if (tid < 8 * DD) {
    int c = tid / DD, d = tid % DD;
    comb[tid] = bond[(0 * 6 + (c & 1)) * DD + d] +
                bond[(1 * 6 + ((c >> 1) & 1)) * DD + d] +
                bond[(2 * 6 + ((c >> 2) & 1)) * DD + d];
  }
  if (tid < HH) { sb1[tid] = b1l[tid]; ssum[tid] = 0.f; ssq[tid] = 0.f; }
  __syncthreads();

  int b = blockIdx.x;
  int start = bucket_base[b];
  int end = bucket_base[b + 1];
  for (int base = start + tid; base < end; base += 1024) {
    unsigned r[4];
    fv4 A[4], B4[4], C4[4];
#pragma unroll
    for (int k = 0; k < 4; ++k) {
      int idx = base + k * 256;
      if (idx < end) {
        unsigned rr = binned[idx];
        r[k] = rr;
        const fv4* hs = (const fv4*)(hbuf + (size_t)(rr & 0xFFFFFu) * SH);
        A[k] = __builtin_nontemporal_load(&hs[0]);
        B4[k] = __builtin_nontemporal_load(&hs[1]);
        C4[k] = __builtin_nontemporal_load(&hs[2]);
      }
    }
#pragma unroll
    for (int k = 0; k < 4; ++k) {
      int idx = base + k * 256;
      if (idx < end) {
        float hv[DD] = {A[k].x, A[k].y, A[k].z, A[k].w,
                        B4[k].x, B4[k].y, B4[k].z, B4[k].w, C4[k].x};
        const float* cb = comb + (r[k] >> 29) * DD;
        float* sl = slice + ((r[k] >> 20) & 511u) * DD;
#pragma unroll
        for (int d = 0; d < DD; ++d) {
          float m = hv[d] + cb[d];
          m = m > 0.f ? m : 0.f;
          atomicAdd(&sl[d], m);
        }
      }
    }
  }
  __syncthreads();

  // epilogue: 2 nodes/thread: z -> X; per-j immediate stats reduction
  float eps1 = 1.0f + epsp[0];
  size_t n0 = (size_t)b * NPB;
  float z0[DD], z1[DD];
#pragma unroll
  for (int half = 0; half < 2; ++half) {
    int node = half * 256 + tid;
    size_t n = n0 + node;
    const float4* hr = (const float4*)(hbuf + n * SH);
    float4 HA = hr[0], HB = hr[1], HC = hr[2];
    float hi[DD] = {HA.x, HA.y, HA.z, HA.w, HB.x, HB.y, HB.z, HB.w, HC.x};
    float* zz = half ? z1 : z0;
#pragma unroll
    for (int d = 0; d < DD; ++d) zz[d] = eps1 * hi[d] + slice[node * DD + d];
    float* xo = X + n * SX;
    ((float4*)xo)[0] = make_float4(zz[0], zz[1], zz[2], zz[3]);
    ((float4*)xo)[1] = make_float4(zz[4], zz[5], zz[6], zz[7]);
    xo[8] = zz[8];
  }
  int lane0 = ((tid & 63) == 0);
#pragma unroll
  for (int j = 0; j < HH; ++j) {
    float a0 = sb1[j], a1 = sb1[j];
#pragma unroll
    for (int d = 0; d < DD; ++d) {
      a0 += z0[d] * sW1[d * HH + j];
      a1 += z1[d] * sW1[d * HH + j];
    }
    float rs = waveReduce(a0 + a1);
    float rq = waveReduce(a0 * a0 + a1 * a1);
    if (lane0) { atomicAdd(&ssum[j], rs); atomicAdd(&ssq[j], rq); }
  }
  __syncthreads();
  if (tid < HH) {
    atomicAdd(&stats[SUM1 + tid], ssum[tid]);
    atomicAdd(&stats[SQ1 + tid], ssq[tid]);
  }
}

// in-place X: z2 = relu(bn1(z@W1+b1)) @ W2 + b2;  BN2 stats. bnfin folded in.
__global__ void __launch_bounds__(256)
k_partB(float* __restrict__ X, const float* __restrict__ W1l, const float* __restrict__ b1l,
        const float* __restrict__ g1, const float* __restrict__ be1,
        const float* __restrict__ W2l, const float* __restrict__ b2l,
        float* __restrict__ stats) {
  __shared__ float sW1[DD * HH], sW2[HH * DD], sb1[HH], sb2[DD];
  __shared__ float sc1[HH], sh1[HH], ssum[DD], ssq[DD];
  int tid = threadIdx.x;
  for (int i = tid; i < DD * HH; i += 256) sW1[i] = W1l[i];
  for (int i = tid; i < HH * DD; i += 256) sW2[i] = W2l[i];
  if (tid < HH) {
    float mean = stats[SUM1 + tid] * (1.0f / NN);
    float var = stats[SQ1 + tid] * (1.0f / NN) - mean * mean;
    float sc = g1[tid] * rsqrtf(var + BN_EPS);
    sc1[tid] = sc;
    sh1[tid] = be1[tid] - mean * sc;
    sb1[tid] = b1l[tid];
  }
  if (tid < DD) { sb2[tid] = b2l[tid]; ssum[tid] = 0.f; ssq[tid] = 0.f; }
  __syncthreads();
  size_t n = (size_t)blockIdx.x * 256 + tid;
  float* xr = X + n * SX;
  float4 XA = ((float4*)xr)[0], XB = ((float4*)xr)[1];
  float x8 = xr[8];
  float z[DD] = {XA.x, XA.y, XA.z, XA.w, XB.x, XB.y, XB.z, XB.w, x8};
  float t[HH];
#pragma unroll
  for (int j = 0; j < HH; ++j) {
    float a = sb1[j];
#pragma unroll
    for (int d = 0; d < DD; ++d) a += z[d] * sW1[d * HH + j];
    a = a * sc1[j] + sh1[j];
    t[j] = a > 0.f ? a : 0.f;
  }
  float z2[DD];
  int lane0 = ((tid & 63) == 0);
#pragma unroll
  for (int d = 0; d < DD; ++d) {
    float a = sb2[d];
#pragma unroll
    for (int j = 0; j < HH; ++j) a += t[j] * sW2[j * DD + d];
    z2[d] = a;
    float rs = waveReduce(a);
    float rq = waveReduce(a * a);
    if (lane0) { atomicAdd(&ssum[d], rs); atomicAdd(&ssq[d], rq); }
  }
  ((float4*)xr)[0] = make_float4(z2[0], z2[1], z2[2], z2[3]);
  ((float4*)xr)[1] = make_float4(z2[4], z2[5], z2[6], z2[7]);
  xr[8] = z2[8];
  __syncthreads();
  if (tid < DD) {
    atomicAdd(&stats[SUM2 + tid], ssum[tid]);
    atomicAdd(&stats[SQ2 + tid], ssq[tid]);
  }
}

// h_new = bn2(z2)[relu] + h_in; if vn_next: hbuf = h_new + vn_next[batch]
// (+ optional vnsum segsum); else (last layer) accumulate column sums into out.
__global__ void __launch_bounds__(256)
k_partC(const float* __restrict__ X, float* __restrict__ hbuf,
        const float* __restrict__ stats, const float* __restrict__ g2,
        const float* __restrict__ be2, const int* __restrict__ batch,
        const float* __restrict__ vn_next, float* __restrict__ vnsum_out,
        int do_relu, float* __restrict__ out) {
  __shared__ float sc[DD], sh[DD], ssum[DD];
  int tid = threadIdx.x;
  if (tid < DD) {
    float mean = stats[SUM2 + tid] * (1.0f / NN);
    float var = stats[SQ2 + tid] * (1.0f / NN) - mean * mean;
    float s = g2[tid] * rsqrtf(var + BN_EPS);
    sc[tid] = s;
    sh[tid] = be2[tid] - mean * s;
    ssum[tid] = 0.f;
  }
  __syncthreads();
  size_t n = (size_t)blockIdx.x * 256 + tid;
  const float* xr = X + n * SX;
  float4 XA = ((const float4*)xr)[0], XB = ((const float4*)xr)[1];
  float x8 = xr[8];
  float zv[DD] = {XA.x, XA.y, XA.z, XA.w, XB.x, XB.y, XB.z, XB.w, x8};
  float* hr = hbuf + n * SH;
  float4 HA = ((float4*)hr)[0], HB = ((float4*)hr)[1], HC = ((float4*)hr)[2];
  float hi[DD] = {HA.x, HA.y, HA.z, HA.w, HB.x, HB.y, HB.z, HB.w, HC.x};
  float hv[DD];
#pragma unroll
  for (int d = 0; d < DD; ++d) {
    float z = zv[d] * sc[d] + sh[d];
    if (do_relu) z = z > 0.f ? z : 0.f;
    hv[d] = z + hi[d];
  }
  if (vn_next != nullptr) {
    int g = batch[n];
#pragma unroll
    for (int d = 0; d < DD; ++d) hv[d] += vn_next[(size_t)g * DD + d];
    ((float4*)hr)[0] = make_float4(hv[0], hv[1], hv[2], hv[3]);
    ((float4*)hr)[1] = make_float4(hv[4], hv[5], hv[6], hv[7]);
    hr[8] = hv[8];
    if (vnsum_out != nullptr) {
      int lane = tid & 63;
      float s[DD];
#pragma unroll
      for (int d = 0; d < DD; ++d) s[d] = hv[d];
#pragma unroll
      for (int st = 1; st < 64; st <<= 1) {
        int gu = __shfl_up(g, st, 64);
        bool ok = (lane >= st) && (gu == g);
#pragma unroll
        for (int d = 0; d < DD; ++d) {
          float vu = __shfl_up(s[d], st, 64);
          if (ok) s[d] += vu;
        }
      }
      int gn = __shfl_down(g, 1, 64);
      if ((lane == 63) || (gn != g)) {
#pragma unroll
        for (int d = 0; d < DD; ++d) atomicAdd(&vnsum_out[(size_t)g * DD + d], s[d]);
      }
    }
  } else {
    int lane0 = ((tid & 63) == 0);
#pragma unroll
    for (int d = 0; d < DD; ++d) {
      float r = waveReduce(hv[d]);
      if (lane0) atomicAdd(&ssum[d], r);
    }
    __syncthreads();
    if (tid < DD) atomicAdd(&out[tid], ssum[tid]);
  }
}

// ---------------- virtual-node MLP ----------------

__global__ void k_vnA(const float* __restrict__ vnsum, const float* __restrict__ vn,
                      float* __restrict__ vt1, const float* __restrict__ W1l,
                      const float* __restrict__ b1l, float* __restrict__ stats) {
  __shared__ float sW[DD * HH], sb[HH], ssum[HH], ssq[HH];
  int tid = threadIdx.x;
  for (int i = tid; i < DD * HH; i += 256) sW[i] = W1l[i];
  if (tid < HH) { sb[tid] = b1l[tid]; ssum[tid] = 0.f; ssq[tid] = 0.f; }
  __syncthreads();
  size_t g = (size_t)blockIdx.x * 256 + tid;
  float r[DD];
#pragma unroll
  for (int d = 0; d < DD; ++d) r[d] = vnsum[g * DD + d] + vn[g * DD + d];
  int lane0 = ((tid & 63) == 0);
#pragma unroll
  for (int j = 0; j < HH; ++j) {
    float a = sb[j];
#pragma unroll
    for (int d = 0; d < DD; ++d) a += r[d] * sW[d * HH + j];
    vt1[g * HH + j] = a;
    float rs = waveReduce(a);
    float rq = waveReduce(a * a);
    if (lane0) { atomicAdd(&ssum[j], rs); atomicAdd(&ssq[j], rq); }
  }
  __syncthreads();
  if (tid < HH) {
    atomicAdd(&stats[VSUM1 + tid], ssum[tid]);
    atomicAdd(&stats[VSQ1 + tid], ssq[tid]);
  }
}

__global__ void k_vnB(const float* __restrict__ vt1, float* __restrict__ vt2,
                      const float* __restrict__ W2l, const float* __restrict__ b2l,
                      const float* __restrict__ g1, const float* __restrict__ be1,
                      float* __restrict__ stats) {
  __shared__ float sW2[HH * DD], sb2[DD], sc1[HH], sh1[HH], ssum[DD], ssq[DD];
  int tid = threadIdx.x;
  for (int i = tid; i < HH * DD; i += 256) sW2[i] = W2l[i];
  if (tid < HH) {
    float mean = stats[VSUM1 + tid] * (1.0f / NG);
    float var = stats[VSQ1 + tid] * (1.0f / NG) - mean * mean;
    float sc = g1[tid] * rsqrtf(var + BN_EPS);
    sc1[tid] = sc;
    sh1[tid] = be1[tid] - mean * sc;
  }
  if (tid < DD) { sb2[tid] = b2l[tid]; ssum[tid] = 0.f; ssq[tid] = 0.f; }
  __syncthreads();
  size_t g = (size_t)blockIdx.x * 256 + tid;
  float t[HH];
#pragma unroll
  for (int j = 0; j < HH; ++j) {
    float a = vt1[g * HH + j] * sc1[j] + sh1[j];
    t[j] = a > 0.f ? a : 0.f;
  }
  int lane0 = ((tid & 63) == 0);
#pragma unroll
  for (int d = 0; d < DD; ++d) {
    float a = sb2[d];
#pragma unroll
    for (int j = 0; j < HH; ++j) a += t[j] * sW2[j * DD + d];
    vt2[g * DD + d] = a;
    float rs = waveReduce(a);
    float rq = waveReduce(a * a);
    if (lane0) { atomicAdd(&ssum[d], rs); atomicAdd(&ssq[d], rq); }
  }
  __syncthreads();
  if (tid < DD) {
    atomicAdd(&stats[VSUM2 + tid], ssum[tid]);
    atomicAdd(&stats[VSQ2 + tid], ssq[tid]);
  }
}

__global__ void k_vnC(const float* __restrict__ vt2, float* __restrict__ vn,
                      const float* __restrict__ g2, const float* __restrict__ be2,
                      const float* __restrict__ stats) {
  __shared__ float sc[DD], sh[DD];
  int tid = threadIdx.x;
  if (tid < DD) {
    float mean = stats[VSUM2 + tid] * (1.0f / NG);
    float var = stats[VSQ2 + tid] * (1.0f / NG) - mean * mean;
    float s = g2[tid] * rsqrtf(var + BN_EPS);
    sc[tid] = s;
    sh[tid] = be2[tid] - mean * s;
  }
  __syncthreads();
  size_t g = (size_t)blockIdx.x * 256 + tid;
#pragma unroll
  for (int d = 0; d < DD; ++d) {
    float v = vt2[g * DD + d] * sc[d] + sh[d];
    v = v > 0.f ? v : 0.f;
    vn[g * DD + d] += v;
  }
}

extern "C" void kernel_launch(void* const* d_in, const int* in_sizes, int n_in,
                              void* d_out, int out_size, void* d_ws, size_t ws_size,
                              hipStream_t stream) {
  const float* atom_emb = (const float*)d_in[0];
  const float* bond_emb = (const float*)d_in[1];
  const float* eps_gin  = (const float*)d_in[2];
  const float* W1   = (const float*)d_in[3];
  const float* b1   = (const float*)d_in[4];
  const float* bn1_g = (const float*)d_in[5];
  const float* bn1_b = (const float*)d_in[6];
  const float* W2   = (const float*)d_in[7];
  const float* b2   = (const float*)d_in[8];
  const float* bno_g = (const float*)d_in[9];
  const float* bno_b = (const float*)d_in[10];
  const float* vnW1 = (const float*)d_in[11];
  const float* vnb1 = (const float*)d_in[12];
  const float* vnbn1_g = (const float*)d_in[13];
  const float* vnbn1_b = (const float*)d_in[14];
  const float* vnW2 = (const float*)d_in[15];
  const float* vnb2 = (const float*)d_in[16];
  const float* vnbn2_g = (const float*)d_in[17];
  const float* vnbn2_b = (const float*)d_in[18];
  const int* x          = (const int*)d_in[19];
  const int* edge_index = (const int*)d_in[20];
  const int* edge_attr  = (const int*)d_in[21];
  const int* batch      = (const int*)d_in[22];
  float* out = (float*)d_out;

  // workspace layout (floats) — ~156 MB
  float* hbuf  = (float*)d_ws;                         // NN*SH (64B rows)
  float* X     = hbuf + (size_t)NN * SH;               // NN*SX
  unsigned* binned = (unsigned*)(X + (size_t)NN * SX); // NE uint32
  uint2* coarse = (uint2*)d_ws;                        // overlays hbuf (dead until k_atom)
  float* vn    = (float*)(binned + (size_t)NE);        // NG*DD
  float* vnsum = vn + (size_t)NG * DD;                 // NG*DD (vt2 overlays)
  float* vt2   = vnsum;
  float* vt1   = vnsum + (size_t)NG * DD;              // NG*HH
  float* stats = vt1 + (size_t)NG * HH;                // STATS_FLOATS
  int* bucket_count  = (int*)(stats + STATS_FLOATS);   // NB
  int* bucket_base   = bucket_count + NB;              // NB+1
  int* bucket_cursor = bucket_base + NB + 1;           // NB
  int* group_cursor  = bucket_cursor + NB;             // NGRP*16 (padded)

  // ---- one-time binning (before k_atom: coarse overlays hbuf/X space) ----
  (void)hipMemsetAsync(bucket_count, 0, NB * sizeof(int), stream);
  k_count<<<2048, 256, 0, stream>>>(edge_index, bucket_count);
  k_scan<<<1, 256, 0, stream>>>(bucket_count, bucket_base, bucket_cursor, group_cursor);
  k_p1<<<512, 256, 0, stream>>>(edge_index, edge_attr, group_cursor, coarse);
  k_p2<<<NGRP * 8, 256, 0, stream>>>(coarse, bucket_base, bucket_cursor, binned);

  (void)hipMemsetAsync(vn, 0, (size_t)2 * NG * DD * sizeof(float), stream);  // vn + vnsum
  (void)hipMemsetAsync(out, 0, (size_t)DD * sizeof(float), stream);
  k_atom<<<NN / 256, 256, 0, stream>>>(atom_emb, x, batch, hbuf, vnsum);

  for (int l = 0; l < 3; ++l) {
    int has_vn = (l < 2);
    (void)hipMemsetAsync(stats, 0, STATS_FLOATS * sizeof(float), stream);
    if (has_vn) {
      k_vnA<<<NG / 256, 256, 0, stream>>>(vnsum, vn, vt1, vnW1 + (size_t)l * DD * HH,
                                          vnb1 + (size_t)l * HH, stats);
      k_vnB<<<NG / 256, 256, 0, stream>>>(vt1, vt2, vnW2 + (size_t)l * HH * DD,
                                          vnb2 + (size_t)l * DD,
                                          vnbn1_g + (size_t)l * HH, vnbn1_b + (size_t)l * HH,
                                          stats);
      k_vnC<<<NG / 256, 256, 0, stream>>>(vt2, vn, vnbn2_g + (size_t)l * DD,
                                          vnbn2_b + (size_t)l * DD, stats);
    }
    k_edgeA<<<NB, 256, 0, stream>>>(hbuf, binned, bucket_base,
                                    bond_emb + (size_t)l * 3 * 6 * DD,
                                    W1 + (size_t)l * DD * HH, b1 + (size_t)l * HH,
                                    eps_gin + l, X, stats);
    k_partB<<<NN / 256, 256, 0, stream>>>(X, W1 + (size_t)l * DD * HH,
                                          b1 + (size_t)l * HH,
                                          bn1_g + (size_t)l * HH, bn1_b + (size_t)l * HH,
                                          W2 + (size_t)l * HH * DD, b2 + (size_t)l * DD,
                                          stats);
    if (l == 0)
      (void)hipMemsetAsync(vnsum, 0, (size_t)NG * DD * sizeof(float), stream);
    k_partC<<<NN / 256, 256, 0, stream>>>(X, hbuf, stats,
                                          bno_g + (size_t)l * DD, bno_b + (size_t)l * DD,
                                          batch,
                                          has_vn ? vn : nullptr,
                                          (l == 0) ? vnsum : nullptr,
                                          has_vn ? 1 : 0,
                                          (l == 2) ? out : nullptr);
  }
}

// Round 8
// 2249.130 us; speedup vs baseline: 1.5006x; 1.1678x over previous
//
#include <hip/hip_runtime.h>

#define NN 1048576   // nodes (= 2^20, src fits 20 bits)
#define NE 8388608   // edges
#define NG 32768     // graphs
#define DD 9         // emb dim
#define SB 12        // hbuf/X row stride (48B, sequential access only)
#define HH 18        // hidden
#define BN_EPS 1e-5f

#define NPB 512      // nodes per fine bucket
#define NB  2048     // fine buckets
#define NGRP 64      // coarse dst-groups

// spread stats: 64 copies x 64 chans. within-copy offsets:
#define NSUM1 0      // 18
#define NSQ1  18     // 18
#define NSUM2 36     // 9
#define NSQ2  45     // 9
#define OUTS  54     // 9
#define VBASE 4096   // VN stats (single copy)
#define VSUM1 (VBASE+0)
#define VSQ1  (VBASE+18)
#define VSUM2 (VBASE+36)
#define VSQ2  (VBASE+45)
#define STATS_FLOATS 4224

typedef float fv4 __attribute__((ext_vector_type(4)));
typedef unsigned uv4 __attribute__((ext_vector_type(4)));

__device__ __forceinline__ float waveReduce(float v) {
#pragma unroll
  for (int off = 32; off > 0; off >>= 1) v += __shfl_down(v, off, 64);
  return v;
}
__device__ __forceinline__ unsigned bf16rne(float f) {
  unsigned u = __float_as_uint(f);
  return (u + 0x7FFFu + ((u >> 16) & 1u)) >> 16;
}
__device__ __forceinline__ float bf2f(unsigned s) { return __uint_as_float(s << 16); }

// ---------------- binning (coalesced two-pass, once per launch) ----------------

__global__ void k_count(const int* __restrict__ ei, int* __restrict__ bucket_count) {
  __shared__ int hist[NB];
  for (int i = threadIdx.x; i < NB; i += 256) hist[i] = 0;
  __syncthreads();
  const int CH = NE / 2048;
  int base = blockIdx.x * CH;
  for (int i = threadIdx.x; i < CH; i += 256)
    atomicAdd(&hist[ei[NE + base + i] >> 9], 1);
  __syncthreads();
  for (int i = threadIdx.x; i < NB; i += 256)
    if (hist[i]) atomicAdd(&bucket_count[i], hist[i]);
}

__global__ void k_scan(const int* __restrict__ bucket_count, int* __restrict__ bucket_base,
                       int* __restrict__ bucket_cursor, int* __restrict__ group_cursor) {
  __shared__ int tsum[256];
  int tid = threadIdx.x;
  int c[8];
  int run = 0;
#pragma unroll
  for (int k = 0; k < 8; ++k) { c[k] = bucket_count[tid * 8 + k]; run += c[k]; }
  tsum[tid] = run;
  __syncthreads();
  for (int off = 1; off < 256; off <<= 1) {
    int v = (tid >= off) ? tsum[tid - off] : 0;
    __syncthreads();
    tsum[tid] += v;
    __syncthreads();
  }
  int excl = tsum[tid] - run;
  if ((tid & 3) == 0) group_cursor[(tid >> 2) * 16] = excl;
#pragma unroll
  for (int k = 0; k < 8; ++k) {
    bucket_base[tid * 8 + k] = excl;
    bucket_cursor[tid * 8 + k] = excl;
    excl += c[k];
  }
  if (tid == 255) bucket_base[NB] = tsum[255];
}

#define P1K 48
__global__ void __launch_bounds__(256)
k_p1(const int* __restrict__ ei, const int* __restrict__ ea,
     int* __restrict__ group_cursor, uint2* __restrict__ coarse) {
  __shared__ uint2 stage[NGRP * P1K];
  __shared__ int scnt[NGRP], gbase[NGRP];
  int tid = threadIdx.x;
  for (int i = tid; i < NGRP; i += 256) scnt[i] = 0;
  __syncthreads();
  const int CH = NE / 512;
  int base = blockIdx.x * CH;
  for (int batch = 0; batch < CH / 1024; ++batch) {
#pragma unroll
    for (int k = 0; k < 4; ++k) {
      int e = base + batch * 1024 + k * 256 + tid;
      int s = ei[e];
      int d = ei[NE + e];
      unsigned at = (unsigned)((ea[(size_t)e * 3 + 0] & 1) |
                               ((ea[(size_t)e * 3 + 1] & 1) << 1) |
                               ((ea[(size_t)e * 3 + 2] & 1) << 2));
      int g = d >> 14;
      uint2 rec = make_uint2((unsigned)s | (at << 20), (unsigned)d);
      int pos = atomicAdd(&scnt[g], 1);
      if (pos < P1K) stage[g * P1K + pos] = rec;
      else coarse[atomicAdd(&group_cursor[g * 16], 1)] = rec;
    }
    __syncthreads();
    {
      int g = tid >> 2, j = tid & 3;
      int cnt = min(scnt[g], P1K);
      if (j == 0) gbase[g] = cnt ? atomicAdd(&group_cursor[g * 16], cnt) : 0;
      __syncthreads();
      for (int i = j; i < cnt; i += 4) coarse[gbase[g] + i] = stage[g * P1K + i];
    }
    __syncthreads();
    if (tid < NGRP) scnt[tid] = 0;
    __syncthreads();
  }
}

#define P2K 48
__global__ void __launch_bounds__(256)
k_p2(const uint2* __restrict__ coarse, const int* __restrict__ bucket_base,
     int* __restrict__ bucket_cursor, unsigned* __restrict__ binned) {
  __shared__ unsigned stage[32 * P2K];
  __shared__ int scnt[32], gbase[32];
  int tid = threadIdx.x;
  int g = blockIdx.x >> 3;
  int sub = blockIdx.x & 7;
  int s0 = bucket_base[g << 5];
  int s1 = bucket_base[(g + 1) << 5];
  int len = s1 - s0;
  int chunk = (len + 7) >> 3;
  int my0 = s0 + sub * chunk;
  int my1 = min(my0 + chunk, s1);
  if (tid < 32) scnt[tid] = 0;
  __syncthreads();
  for (int b0 = my0; b0 < my1; b0 += 1024) {
#pragma unroll
    for (int k = 0; k < 4; ++k) {
      int i = b0 + k * 256 + tid;
      if (i < my1) {
        uint2 rec = coarse[i];
        unsigned s = rec.x & 0xFFFFFu;
        unsigned at = rec.x >> 20;
        unsigned d = rec.y;
        int bt = (int)((d >> 9) & 31u);
        unsigned o = s | ((d & 511u) << 20) | (at << 29);
        int pos = atomicAdd(&scnt[bt], 1);
        if (pos < P2K) stage[bt * P2K + pos] = o;
        else binned[atomicAdd(&bucket_cursor[(g << 5) | bt], 1)] = o;
      }
    }
    __syncthreads();
    {
      int bt = tid >> 3, j = tid & 7;
      int cnt = min(scnt[bt], P2K);
      if (j == 0) gbase[bt] = cnt ? atomicAdd(&bucket_cursor[(g << 5) | bt], cnt) : 0;
      __syncthreads();
      for (int i = j; i < cnt; i += 8) binned[gbase[bt] + i] = stage[bt * P2K + i];
    }
    __syncthreads();
    if (tid < 32) scnt[tid] = 0;
    __syncthreads();
  }
}

// ---------------- per-layer kernels ----------------

__device__ __forceinline__ void writeMirror(unsigned* __restrict__ hm8,
                                            unsigned short* __restrict__ hm1,
                                            size_t n, const float* hv) {
  uv4 q;
  q.x = bf16rne(hv[0]) | (bf16rne(hv[1]) << 16);
  q.y = bf16rne(hv[2]) | (bf16rne(hv[3]) << 16);
  q.z = bf16rne(hv[4]) | (bf16rne(hv[5]) << 16);
  q.w = bf16rne(hv[6]) | (bf16rne(hv[7]) << 16);
  *(uv4*)(hm8 + n * 4) = q;
  hm1[n] = (unsigned short)bf16rne(hv[8]);
}

// h_in(0) = atom embed sum; mirrors; vnsum0 = segsum
__global__ void k_atom(const float* __restrict__ atom_emb, const int* __restrict__ x,
                       const int* __restrict__ batch, float* __restrict__ h,
                       unsigned* __restrict__ hm8, unsigned short* __restrict__ hm1,
                       float* __restrict__ vnsum) {
  int n = blockIdx.x * 256 + threadIdx.x;
  int xi[9];
#pragma unroll
  for (int f = 0; f < 9; ++f) xi[f] = x[(size_t)n * 9 + f];
  float acc[DD] = {0.f,0.f,0.f,0.f,0.f,0.f,0.f,0.f,0.f};
#pragma unroll
  for (int f = 0; f < 9; ++f) {
    const float* row = atom_emb + ((size_t)f * 119 + xi[f]) * DD;
#pragma unroll
    for (int d = 0; d < DD; ++d) acc[d] += row[d];
  }
  float* o = h + (size_t)n * SB;
  ((float4*)o)[0] = make_float4(acc[0], acc[1], acc[2], acc[3]);
  ((float4*)o)[1] = make_float4(acc[4], acc[5], acc[6], acc[7]);
  o[8] = acc[8];
  writeMirror(hm8, hm1, (size_t)n, acc);
  int g = batch[n];
  int lane = threadIdx.x & 63;
  float s[DD];
#pragma unroll
  for (int d = 0; d < DD; ++d) s[d] = acc[d];
#pragma unroll
  for (int st = 1; st < 64; st <<= 1) {
    int gu = __shfl_up(g, st, 64);
    bool ok = (lane >= st) && (gu == g);
#pragma unroll
    for (int d = 0; d < DD; ++d) {
      float vu = __shfl_up(s[d], st, 64);
      if (ok) s[d] += vu;
    }
  }
  int gn = __shfl_down(g, 1, 64);
  if ((lane == 63) || (gn != g)) {
#pragma unroll
    for (int d = 0; d < DD; ++d) atomicAdd(&vnsum[(size_t)g * DD + d], s[d]);
  }
}

// Fused: LDS-aggregate bf16-mirror messages; z=(1+eps)h_in+aggr -> X; BN1 stats (spread)
__global__ void __launch_bounds__(256)
k_edgeA(const float* __restrict__ hbuf, const unsigned* __restrict__ hm8,
        const unsigned short* __restrict__ hm1, const unsigned* __restrict__ binned,
        const int* __restrict__ bucket_base, const float* __restrict__ bond,
        const float* __restrict__ W1l, const float* __restrict__ b1l,
        const float* __restrict__ epsp, float* __restrict__ X,
        float* __restrict__ stats) {
  __shared__ float slice[NPB * DD];   // 18 KB
  __shared__ float comb[8 * DD];
  __shared__ float sW1[DD * HH], sb1[HH], ssum[HH], ssq[HH];
  int tid = threadIdx.x;
  for (int i = tid; i < NPB * DD; i += 256) slice[i] = 0.f;
  for (int i = tid; i < DD * HH; i += 256) sW1[i] = W1l[i];
  if (tid < 8 * DD) {
    int c = tid / DD, d = tid % DD;
    comb[tid] = bond[(0 * 6 + (c & 1)) * DD + d] +
                bond[(1 * 6 + ((c >> 1) & 1)) * DD + d] +
                bond[(2 * 6 + ((c >> 2) & 1)) * DD + d];
  }
  if (tid < HH) { sb1[tid] = b1l[tid]; ssum[tid] = 0.f; ssq[tid] = 0.f; }
  __syncthreads();

  int b = blockIdx.x;
  int start = bucket_base[b];
  int end = bucket_base[b + 1];
  for (int base = start + tid; base < end; base += 1024) {
    unsigned r[4];
    uv4 q[4];
    unsigned short d8[4];
#pragma unroll
    for (int k = 0; k < 4; ++k) {
      int idx = base + k * 256;
      if (idx < end) {
        unsigned rr = __builtin_nontemporal_load(&binned[idx]);
        r[k] = rr;
        unsigned src = rr & 0xFFFFFu;
        q[k] = __builtin_nontemporal_load((const uv4*)(hm8 + (size_t)src * 4));
        d8[k] = hm1[src];   // 2 MB plane: keep cached
      }
    }
#pragma unroll
    for (int k = 0; k < 4; ++k) {
      int idx = base + k * 256;
      if (idx < end) {
        float hv[DD] = {bf2f(q[k].x & 0xFFFFu), bf2f(q[k].x >> 16),
                        bf2f(q[k].y & 0xFFFFu), bf2f(q[k].y >> 16),
                        bf2f(q[k].z & 0xFFFFu), bf2f(q[k].z >> 16),
                        bf2f(q[k].w & 0xFFFFu), bf2f(q[k].w >> 16),
                        bf2f((unsigned)d8[k])};
        const float* cb = comb + (r[k] >> 29) * DD;
        float* sl = slice + ((r[k] >> 20) & 511u) * DD;
#pragma unroll
        for (int d = 0; d < DD; ++d) {
          float m = hv[d] + cb[d];
          m = m > 0.f ? m : 0.f;
          atomicAdd(&sl[d], m);
        }
      }
    }
  }
  __syncthreads();

  float eps1 = 1.0f + epsp[0];
  size_t n0 = (size_t)b * NPB;
  float z0[DD], z1[DD];
#pragma unroll
  for (int half = 0; half < 2; ++half) {
    int node = half * 256 + tid;
    size_t n = n0 + node;
    const float* hr = hbuf + n * SB;
    float4 HA = ((const float4*)hr)[0], HB = ((const float4*)hr)[1];
    float h8 = hr[8];
    float hi[DD] = {HA.x, HA.y, HA.z, HA.w, HB.x, HB.y, HB.z, HB.w, h8};
    float* zz = half ? z1 : z0;
#pragma unroll
    for (int d = 0; d < DD; ++d) zz[d] = eps1 * hi[d] + slice[node * DD + d];
    float* xo = X + n * SB;
    ((float4*)xo)[0] = make_float4(zz[0], zz[1], zz[2], zz[3]);
    ((float4*)xo)[1] = make_float4(zz[4], zz[5], zz[6], zz[7]);
    xo[8] = zz[8];
  }
  int lane0 = ((tid & 63) == 0);
#pragma unroll
  for (int j = 0; j < HH; ++j) {
    float a0 = sb1[j], a1 = sb1[j];
#pragma unroll
    for (int d = 0; d < DD; ++d) {
      a0 += z0[d] * sW1[d * HH + j];
      a1 += z1[d] * sW1[d * HH + j];
    }
    float rs = waveReduce(a0 + a1);
    float rq = waveReduce(a0 * a0 + a1 * a1);
    if (lane0) { atomicAdd(&ssum[j], rs); atomicAdd(&ssq[j], rq); }
  }
  __syncthreads();
  int copy = (b & 63) * 64;
  if (tid < HH) {
    atomicAdd(&stats[copy + NSUM1 + tid], ssum[tid]);
    atomicAdd(&stats[copy + NSQ1 + tid], ssq[tid]);
  }
}

// in-place X: z2 = relu(bn1(z@W1+b1)) @ W2 + b2;  BN2 stats (spread)
__global__ void __launch_bounds__(256)
k_partB(float* __restrict__ X, const float* __restrict__ W1l, const float* __restrict__ b1l,
        const float* __restrict__ g1, const float* __restrict__ be1,
        const float* __restrict__ W2l, const float* __restrict__ b2l,
        float* __restrict__ stats) {
  __shared__ float sW1[DD * HH], sW2[HH * DD], sb1[HH], sb2[DD];
  __shared__ float sc1[HH], sh1[HH], ssum[DD], ssq[DD];
  int tid = threadIdx.x;
  for (int i = tid; i < DD * HH; i += 256) sW1[i] = W1l[i];
  for (int i = tid; i < HH * DD; i += 256) sW2[i] = W2l[i];
  if (tid < HH) {
    float s = 0.f, q = 0.f;
#pragma unroll
    for (int c = 0; c < 64; ++c) {
      s += stats[c * 64 + NSUM1 + tid];
      q += stats[c * 64 + NSQ1 + tid];
    }
    float mean = s * (1.0f / NN);
    float var = q * (1.0f / NN) - mean * mean;
    float sc = g1[tid] * rsqrtf(var + BN_EPS);
    sc1[tid] = sc;
    sh1[tid] = be1[tid] - mean * sc;
    sb1[tid] = b1l[tid];
  }
  if (tid < DD) { sb2[tid] = b2l[tid]; ssum[tid] = 0.f; ssq[tid] = 0.f; }
  __syncthreads();
  size_t n = (size_t)blockIdx.x * 256 + tid;
  float* xr = X + n * SB;
  float4 XA = ((float4*)xr)[0], XB = ((float4*)xr)[1];
  float x8 = xr[8];
  float z[DD] = {XA.x, XA.y, XA.z, XA.w, XB.x, XB.y, XB.z, XB.w, x8};
  float t[HH];
#pragma unroll
  for (int j = 0; j < HH; ++j) {
    float a = sb1[j];
#pragma unroll
    for (int d = 0; d < DD; ++d) a += z[d] * sW1[d * HH + j];
    a = a * sc1[j] + sh1[j];
    t[j] = a > 0.f ? a : 0.f;
  }
  float z2[DD];
  int lane0 = ((tid & 63) == 0);
#pragma unroll
  for (int d = 0; d < DD; ++d) {
    float a = sb2[d];
#pragma unroll
    for (int j = 0; j < HH; ++j) a += t[j] * sW2[j * DD + d];
    z2[d] = a;
    float rs = waveReduce(a);
    float rq = waveReduce(a * a);
    if (lane0) { atomicAdd(&ssum[d], rs); atomicAdd(&ssq[d], rq); }
  }
  ((float4*)xr)[0] = make_float4(z2[0], z2[1], z2[2], z2[3]);
  ((float4*)xr)[1] = make_float4(z2[4], z2[5], z2[6], z2[7]);
  xr[8] = z2[8];
  __syncthreads();
  int copy = ((int)blockIdx.x & 63) * 64;
  if (tid < DD) {
    atomicAdd(&stats[copy + NSUM2 + tid], ssum[tid]);
    atomicAdd(&stats[copy + NSQ2 + tid], ssq[tid]);
  }
}

// h_new = bn2(z2)[relu] + h_in; vn add + mirrors; last layer: spread out-sums
__global__ void __launch_bounds__(256)
k_partC(const float* __restrict__ X, float* __restrict__ hbuf,
        unsigned* __restrict__ hm8, unsigned short* __restrict__ hm1,
        float* __restrict__ stats, const float* __restrict__ g2,
        const float* __restrict__ be2, const int* __restrict__ batch,
        const float* __restrict__ vn_next, float* __restrict__ vnsum_out,
        int do_relu) {
  __shared__ float sc[DD], sh[DD], ssum[DD];
  int tid = threadIdx.x;
  if (tid < DD) {
    float s = 0.f, q = 0.f;
#pragma unroll
    for (int c = 0; c < 64; ++c) {
      s += stats[c * 64 + NSUM2 + tid];
      q += stats[c * 64 + NSQ2 + tid];
    }
    float mean = s * (1.0f / NN);
    float var = q * (1.0f / NN) - mean * mean;
    float sg = g2[tid] * rsqrtf(var + BN_EPS);
    sc[tid] = sg;
    sh[tid] = be2[tid] - mean * sg;
    ssum[tid] = 0.f;
  }
  __syncthreads();
  size_t n = (size_t)blockIdx.x * 256 + tid;
  const float* xr = X + n * SB;
  float4 XA = ((const float4*)xr)[0], XB = ((const float4*)xr)[1];
  float x8 = xr[8];
  float zv[DD] = {XA.x, XA.y, XA.z, XA.w, XB.x, XB.y, XB.z, XB.w, x8};
  float* hr = hbuf + n * SB;
  float4 HA = ((float4*)hr)[0], HB = ((float4*)hr)[1];
  float h8 = hr[8];
  float hi[DD] = {HA.x, HA.y, HA.z, HA.w, HB.x, HB.y, HB.z, HB.w, h8};
  float hv[DD];
#pragma unroll
  for (int d = 0; d < DD; ++d) {
    float z = zv[d] * sc[d] + sh[d];
    if (do_relu) z = z > 0.f ? z : 0.f;
    hv[d] = z + hi[d];
  }
  if (vn_next != nullptr) {
    int g = batch[n];
#pragma unroll
    for (int d = 0; d < DD; ++d) hv[d] += vn_next[(size_t)g * DD + d];
    ((float4*)hr)[0] = make_float4(hv[0], hv[1], hv[2], hv[3]);
    ((float4*)hr)[1] = make_float4(hv[4], hv[5], hv[6], hv[7]);
    hr[8] = hv[8];
    writeMirror(hm8, hm1, n, hv);
    if (vnsum_out != nullptr) {
      int lane = tid & 63;
      float s[DD];
#pragma unroll
      for (int d = 0; d < DD; ++d) s[d] = hv[d];
#pragma unroll
      for (int st = 1; st < 64; st <<= 1) {
        int gu = __shfl_up(g, st, 64);
        bool ok = (lane >= st) && (gu == g);
#pragma unroll
        for (int d = 0; d < DD; ++d) {
          float vu = __shfl_up(s[d], st, 64);
          if (ok) s[d] += vu;
        }
      }
      int gn = __shfl_down(g, 1, 64);
      if ((lane == 63) || (gn != g)) {
#pragma unroll
        for (int d = 0; d < DD; ++d) atomicAdd(&vnsum_out[(size_t)g * DD + d], s[d]);
      }
    }
  } else {
    int lane0 = ((tid & 63) == 0);
#pragma unroll
    for (int d = 0; d < DD; ++d) {
      float r = waveReduce(hv[d]);
      if (lane0) atomicAdd(&ssum[d], r);
    }
    __syncthreads();
    int copy = ((int)blockIdx.x & 63) * 64;
    if (tid < DD) atomicAdd(&stats[copy + OUTS + tid], ssum[tid]);
  }
}

// reduce spread out-sums -> d_out
__global__ void k_out(const float* __restrict__ stats, float* __restrict__ out) {
  int tid = threadIdx.x;
  if (tid < DD) {
    float s = 0.f;
#pragma unroll
    for (int c = 0; c < 64; ++c) s += stats[c * 64 + OUTS + tid];
    out[tid] = s;
  }
}

// ---------------- virtual-node MLP ----------------

__global__ void k_vnA(const float* __restrict__ vnsum, const float* __restrict__ vn,
                      float* __restrict__ vt1, const float* __restrict__ W1l,
                      const float* __restrict__ b1l, float* __restrict__ stats) {
  __shared__ float sW[DD * HH], sb[HH], ssum[HH], ssq[HH];
  int tid = threadIdx.x;
  for (int i = tid; i < DD * HH; i += 256) sW[i] = W1l[i];
  if (tid < HH) { sb[tid] = b1l[tid]; ssum[tid] = 0.f; ssq[tid] = 0.f; }
  __syncthreads();
  size_t g = (size_t)blockIdx.x * 256 + tid;
  float r[DD];
#pragma unroll
  for (int d = 0; d < DD; ++d) r[d] = vnsum[g * DD + d] + vn[g * DD + d];
  int lane0 = ((tid & 63) == 0);
#pragma unroll
  for (int j = 0; j < HH; ++j) {
    float a = sb[j];
#pragma unroll
    for (int d = 0; d < DD; ++d) a += r[d] * sW[d * HH + j];
    vt1[g * HH + j] = a;
    float rs = waveReduce(a);
    float rq = waveReduce(a * a);
    if (lane0) { atomicAdd(&ssum[j], rs); atomicAdd(&ssq[j], rq); }
  }
  __syncthreads();
  if (tid < HH) {
    atomicAdd(&stats[VSUM1 + tid], ssum[tid]);
    atomicAdd(&stats[VSQ1 + tid], ssq[tid]);
  }
}

__global__ void k_vnB(const float* __restrict__ vt1, float* __restrict__ vt2,
                      const float* __restrict__ W2l, const float* __restrict__ b2l,
                      const float* __restrict__ g1, const float* __restrict__ be1,
                      float* __restrict__ stats) {
  __shared__ float sW2[HH * DD], sb2[DD], sc1[HH], sh1[HH], ssum[DD], ssq[DD];
  int tid = threadIdx.x;
  for (int i = tid; i < HH * DD; i += 256) sW2[i] = W2l[i];
  if (tid < HH) {
    float mean = stats[VSUM1 + tid] * (1.0f / NG);
    float var = stats[VSQ1 + tid] * (1.0f / NG) - mean * mean;
    float sc = g1[tid] * rsqrtf(var + BN_EPS);
    sc1[tid] = sc;
    sh1[tid] = be1[tid] - mean * sc;
  }
  if (tid < DD) { sb2[tid] = b2l[tid]; ssum[tid] = 0.f; ssq[tid] = 0.f; }
  __syncthreads();
  size_t g = (size_t)blockIdx.x * 256 + tid;
  float t[HH];
#pragma unroll
  for (int j = 0; j < HH; ++j) {
    float a = vt1[g * HH + j] * sc1[j] + sh1[j];
    t[j] = a > 0.f ? a : 0.f;
  }
  int lane0 = ((tid & 63) == 0);
#pragma unroll
  for (int d = 0; d < DD; ++d) {
    float a = sb2[d];
#pragma unroll
    for (int j = 0; j < HH; ++j) a += t[j] * sW2[j * DD + d];
    vt2[g * DD + d] = a;
    float rs = waveReduce(a);
    float rq = waveReduce(a * a);
    if (lane0) { atomicAdd(&ssum[d], rs); atomicAdd(&ssq[d], rq); }
  }
  __syncthreads();
  if (tid < DD) {
    atomicAdd(&stats[VSUM2 + tid], ssum[tid]);
    atomicAdd(&stats[VSQ2 + tid], ssq[tid]);
  }
}

__global__ void k_vnC(const float* __restrict__ vt2, float* __restrict__ vn,
                      const float* __restrict__ g2, const float* __restrict__ be2,
                      const float* __restrict__ stats) {
  __shared__ float sc[DD], sh[DD];
  int tid = threadIdx.x;
  if (tid < DD) {
    float mean = stats[VSUM2 + tid] * (1.0f / NG);
    float var = stats[VSQ2 + tid] * (1.0f / NG) - mean * mean;
    float s = g2[tid] * rsqrtf(var + BN_EPS);
    sc[tid] = s;
    sh[tid] = be2[tid] - mean * s;
  }
  __syncthreads();
  size_t g = (size_t)blockIdx.x * 256 + tid;
#pragma unroll
  for (int d = 0; d < DD; ++d) {
    float v = vt2[g * DD + d] * sc[d] + sh[d];
    v = v > 0.f ? v : 0.f;
    vn[g * DD + d] += v;
  }
}

extern "C" void kernel_launch(void* const* d_in, const int* in_sizes, int n_in,
                              void* d_out, int out_size, void* d_ws, size_t ws_size,
                              hipStream_t stream) {
  const float* atom_emb = (const float*)d_in[0];
  const float* bond_emb = (const float*)d_in[1];
  const float* eps_gin  = (const float*)d_in[2];
  const float* W1   = (const float*)d_in[3];
  const float* b1   = (const float*)d_in[4];
  const float* bn1_g = (const float*)d_in[5];
  const float* bn1_b = (const float*)d_in[6];
  const float* W2   = (const float*)d_in[7];
  const float* b2   = (const float*)d_in[8];
  const float* bno_g = (const float*)d_in[9];
  const float* bno_b = (const float*)d_in[10];
  const float* vnW1 = (const float*)d_in[11];
  const float* vnb1 = (const float*)d_in[12];
  const float* vnbn1_g = (const float*)d_in[13];
  const float* vnbn1_b = (const float*)d_in[14];
  const float* vnW2 = (const float*)d_in[15];
  const float* vnb2 = (const float*)d_in[16];
  const float* vnbn2_g = (const float*)d_in[17];
  const float* vnbn2_b = (const float*)d_in[18];
  const int* x          = (const int*)d_in[19];
  const int* edge_index = (const int*)d_in[20];
  const int* edge_attr  = (const int*)d_in[21];
  const int* batch      = (const int*)d_in[22];
  float* out = (float*)d_out;

  // workspace layout (floats) — ~158 MB
  float* hbuf  = (float*)d_ws;                          // NN*SB
  float* X     = hbuf + (size_t)NN * SB;                // NN*SB
  unsigned* hm8 = (unsigned*)(X + (size_t)NN * SB);     // NN uint4 (= NN*4 floats)
  unsigned short* hm1 = (unsigned short*)(hm8 + (size_t)NN * 4);  // NN u16
  unsigned* binned = (unsigned*)((float*)hm1 + (size_t)NN / 2);   // NE u32
  uint2* coarse = (uint2*)d_ws;                         // overlays hbuf+X (dead until k_atom)
  float* vn    = (float*)(binned + (size_t)NE);         // NG*DD
  float* vnsum = vn + (size_t)NG * DD;                  // NG*DD (vt2 overlays)
  float* vt2   = vnsum;
  float* vt1   = vnsum + (size_t)NG * DD;               // NG*HH
  float* stats = vt1 + (size_t)NG * HH;                 // STATS_FLOATS
  int* bucket_count  = (int*)(stats + STATS_FLOATS);    // NB
  int* bucket_base   = bucket_count + NB;               // NB+1
  int* bucket_cursor = bucket_base + NB + 1;            // NB
  int* group_cursor  = bucket_cursor + NB;              // NGRP*16

  // ---- one-time binning ----
  (void)hipMemsetAsync(bucket_count, 0, NB * sizeof(int), stream);
  k_count<<<2048, 256, 0, stream>>>(edge_index, bucket_count);
  k_scan<<<1, 256, 0, stream>>>(bucket_count, bucket_base, bucket_cursor, group_cursor);
  k_p1<<<512, 256, 0, stream>>>(edge_index, edge_attr, group_cursor, coarse);
  k_p2<<<NGRP * 8, 256, 0, stream>>>(coarse, bucket_base, bucket_cursor, binned);

  (void)hipMemsetAsync(vn, 0, (size_t)2 * NG * DD * sizeof(float), stream);
  k_atom<<<NN / 256, 256, 0, stream>>>(atom_emb, x, batch, hbuf, hm8, hm1, vnsum);

  for (int l = 0; l < 3; ++l) {
    int has_vn = (l < 2);
    (void)hipMemsetAsync(stats, 0, STATS_FLOATS * sizeof(float), stream);
    if (has_vn) {
      k_vnA<<<NG / 256, 256, 0, stream>>>(vnsum, vn, vt1, vnW1 + (size_t)l * DD * HH,
                                          vnb1 + (size_t)l * HH, stats);
      k_vnB<<<NG / 256, 256, 0, stream>>>(vt1, vt2, vnW2 + (size_t)l * HH * DD,
                                          vnb2 + (size_t)l * DD,
                                          vnbn1_g + (size_t)l * HH, vnbn1_b + (size_t)l * HH,
                                          stats);
      k_vnC<<<NG / 256, 256, 0, stream>>>(vt2, vn, vnbn2_g + (size_t)l * DD,
                                          vnbn2_b + (size_t)l * DD, stats);
    }
    k_edgeA<<<NB, 256, 0, stream>>>(hbuf, hm8, hm1, binned, bucket_base,
                                    bond_emb + (size_t)l * 3 * 6 * DD,
                                    W1 + (size_t)l * DD * HH, b1 + (size_t)l * HH,
                                    eps_gin + l, X, stats);
    k_partB<<<NN / 256, 256, 0, stream>>>(X, W1 + (size_t)l * DD * HH,
                                          b1 + (size_t)l * HH,
                                          bn1_g + (size_t)l * HH, bn1_b + (size_t)l * HH,
                                          W2 + (size_t)l * HH * DD, b2 + (size_t)l * DD,
                                          stats);
    if (l == 0)
      (void)hipMemsetAsync(vnsum, 0, (size_t)NG * DD * sizeof(float), stream);
    k_partC<<<NN / 256, 256, 0, stream>>>(X, hbuf, hm8, hm1, stats,
                                          bno_g + (size_t)l * DD, bno_b + (size_t)l * DD,
                                          batch,
                                          has_vn ? vn : nullptr,
                                          (l == 0) ? vnsum : nullptr,
                                          has_vn ? 1 : 0);
  }
  k_out<<<1, 64, 0, stream>>>(stats, out);
}

// Round 12
// 2197.592 us; speedup vs baseline: 1.5358x; 1.0235x over previous
//
#include <hip/hip_runtime.h>
#include <hip/hip_fp8.h>

#define NN 1048576   // nodes (= 2^20, src fits 20 bits)
#define NE 8388608   // edges
#define NG 32768     // graphs
#define DD 9         // emb dim
#define SB 12        // hbuf/X row stride (48B, sequential access only)
#define HH 18        // hidden
#define BN_EPS 1e-5f

#define NPB 512      // nodes per fine bucket
#define NB  2048     // fine buckets
#define NGRP 64      // coarse dst-groups

// spread stats: 64 copies x 64 chans. within-copy offsets:
#define NSUM1 0      // 18
#define NSQ1  18     // 18
#define NSUM2 36     // 9
#define NSQ2  45     // 9
#define OUTS  54     // 9
#define VBASE 4096   // VN stats (single copy)
#define VSUM1 (VBASE+0)
#define VSQ1  (VBASE+18)
#define VSUM2 (VBASE+36)
#define VSQ2  (VBASE+45)
#define STATS_FLOATS 4224

typedef float fv4 __attribute__((ext_vector_type(4)));

__device__ __forceinline__ float waveReduce(float v) {
#pragma unroll
  for (int off = 32; off > 0; off >>= 1) v += __shfl_down(v, off, 64);
  return v;
}
__device__ __forceinline__ unsigned f8enc(float f) {
  __hip_fp8_e4m3 v(f);
  return (unsigned)v.__x;
}
__device__ __forceinline__ float f8dec(unsigned b) {
  __hip_fp8_e4m3 v;
  v.__x = (__hip_fp8_storage_t)b;
  return (float)v;
}

// ---------------- binning (coalesced two-pass, once per launch) ----------------

__global__ void k_count(const int* __restrict__ ei, int* __restrict__ bucket_count) {
  __shared__ int hist[NB];
  for (int i = threadIdx.x; i < NB; i += 256) hist[i] = 0;
  __syncthreads();
  const int CH = NE / 2048;
  int base = blockIdx.x * CH;
  for (int i = threadIdx.x; i < CH; i += 256)
    atomicAdd(&hist[ei[NE + base + i] >> 9], 1);
  __syncthreads();
  for (int i = threadIdx.x; i < NB; i += 256)
    if (hist[i]) atomicAdd(&bucket_count[i], hist[i]);
}

__global__ void k_scan(const int* __restrict__ bucket_count, int* __restrict__ bucket_base,
                       int* __restrict__ bucket_cursor, int* __restrict__ group_cursor) {
  __shared__ int tsum[256];
  int tid = threadIdx.x;
  int c[8];
  int run = 0;
#pragma unroll
  for (int k = 0; k < 8; ++k) { c[k] = bucket_count[tid * 8 + k]; run += c[k]; }
  tsum[tid] = run;
  __syncthreads();
  for (int off = 1; off < 256; off <<= 1) {
    int v = (tid >= off) ? tsum[tid - off] : 0;
    __syncthreads();
    tsum[tid] += v;
    __syncthreads();
  }
  int excl = tsum[tid] - run;
  if ((tid & 3) == 0) group_cursor[(tid >> 2) * 16] = excl;
#pragma unroll
  for (int k = 0; k < 8; ++k) {
    bucket_base[tid * 8 + k] = excl;
    bucket_cursor[tid * 8 + k] = excl;
    excl += c[k];
  }
  if (tid == 255) bucket_base[NB] = tsum[255];
}

#define P1K 48
__global__ void __launch_bounds__(256)
k_p1(const int* __restrict__ ei, const int* __restrict__ ea,
     int* __restrict__ group_cursor, uint2* __restrict__ coarse) {
  __shared__ uint2 stage[NGRP * P1K];
  __shared__ int scnt[NGRP], gbase[NGRP];
  int tid = threadIdx.x;
  for (int i = tid; i < NGRP; i += 256) scnt[i] = 0;
  __syncthreads();
  const int CH = NE / 512;
  int base = blockIdx.x * CH;
  for (int batch = 0; batch < CH / 1024; ++batch) {
#pragma unroll
    for (int k = 0; k < 4; ++k) {
      int e = base + batch * 1024 + k * 256 + tid;
      int s = ei[e];
      int d = ei[NE + e];
      unsigned at = (unsigned)((ea[(size_t)e * 3 + 0] & 1) |
                               ((ea[(size_t)e * 3 + 1] & 1) << 1) |
                               ((ea[(size_t)e * 3 + 2] & 1) << 2));
      int g = d >> 14;
      uint2 rec = make_uint2((unsigned)s | (at << 20), (unsigned)d);
      int pos = atomicAdd(&scnt[g], 1);
      if (pos < P1K) stage[g * P1K + pos] = rec;
      else coarse[atomicAdd(&group_cursor[g * 16], 1)] = rec;
    }
    __syncthreads();
    {
      int g = tid >> 2, j = tid & 3;
      int cnt = min(scnt[g], P1K);
      if (j == 0) gbase[g] = cnt ? atomicAdd(&group_cursor[g * 16], cnt) : 0;
      __syncthreads();
      for (int i = j; i < cnt; i += 4) coarse[gbase[g] + i] = stage[g * P1K + i];
    }
    __syncthreads();
    if (tid < NGRP) scnt[tid] = 0;
    __syncthreads();
  }
}

#define P2K 48
__global__ void __launch_bounds__(256)
k_p2(const uint2* __restrict__ coarse, const int* __restrict__ bucket_base,
     int* __restrict__ bucket_cursor, unsigned* __restrict__ binned) {
  __shared__ unsigned stage[32 * P2K];
  __shared__ int scnt[32], gbase[32];
  int tid = threadIdx.x;
  int g = blockIdx.x >> 3;
  int sub = blockIdx.x & 7;
  int s0 = bucket_base[g << 5];
  int s1 = bucket_base[(g + 1) << 5];
  int len = s1 - s0;
  int chunk = (len + 7) >> 3;
  int my0 = s0 + sub * chunk;
  int my1 = min(my0 + chunk, s1);
  if (tid < 32) scnt[tid] = 0;
  __syncthreads();
  for (int b0 = my0; b0 < my1; b0 += 1024) {
#pragma unroll
    for (int k = 0; k < 4; ++k) {
      int i = b0 + k * 256 + tid;
      if (i < my1) {
        uint2 rec = coarse[i];
        unsigned s = rec.x & 0xFFFFFu;
        unsigned at = rec.x >> 20;
        unsigned d = rec.y;
        int bt = (int)((d >> 9) & 31u);
        unsigned o = s | ((d & 511u) << 20) | (at << 29);
        int pos = atomicAdd(&scnt[bt], 1);
        if (pos < P2K) stage[bt * P2K + pos] = o;
        else binned[atomicAdd(&bucket_cursor[(g << 5) | bt], 1)] = o;
      }
    }
    __syncthreads();
    {
      int bt = tid >> 3, j = tid & 7;
      int cnt = min(scnt[bt], P2K);
      if (j == 0) gbase[bt] = cnt ? atomicAdd(&bucket_cursor[(g << 5) | bt], cnt) : 0;
      __syncthreads();
      for (int i = j; i < cnt; i += 8) binned[gbase[bt] + i] = stage[bt * P2K + i];
    }
    __syncthreads();
    if (tid < 32) scnt[tid] = 0;
    __syncthreads();
  }
}

// ---------------- per-layer kernels ----------------

__device__ __forceinline__ void writeMirror(uint2* __restrict__ hmA,
                                            unsigned char* __restrict__ hmB,
                                            size_t n, const float* hv) {
  uint2 q;
  q.x = f8enc(hv[0]) | (f8enc(hv[1]) << 8) | (f8enc(hv[2]) << 16) | (f8enc(hv[3]) << 24);
  q.y = f8enc(hv[4]) | (f8enc(hv[5]) << 8) | (f8enc(hv[6]) << 16) | (f8enc(hv[7]) << 24);
  hmA[n] = q;
  hmB[n] = (unsigned char)f8enc(hv[8]);
}

// h_in(0) = atom embed sum; mirrors; vnsum0 = segsum
__global__ void k_atom(const float* __restrict__ atom_emb, const int* __restrict__ x,
                       const int* __restrict__ batch, float* __restrict__ h,
                       uint2* __restrict__ hmA, unsigned char* __restrict__ hmB,
                       float* __restrict__ vnsum) {
  int n = blockIdx.x * 256 + threadIdx.x;
  int xi[9];
#pragma unroll
  for (int f = 0; f < 9; ++f) xi[f] = x[(size_t)n * 9 + f];
  float acc[DD] = {0.f,0.f,0.f,0.f,0.f,0.f,0.f,0.f,0.f};
#pragma unroll
  for (int f = 0; f < 9; ++f) {
    const float* row = atom_emb + ((size_t)f * 119 + xi[f]) * DD;
#pragma unroll
    for (int d = 0; d < DD; ++d) acc[d] += row[d];
  }
  float* o = h + (size_t)n * SB;
  ((float4*)o)[0] = make_float4(acc[0], acc[1], acc[2], acc[3]);
  ((float4*)o)[1] = make_float4(acc[4], acc[5], acc[6], acc[7]);
  o[8] = acc[8];
  writeMirror(hmA, hmB, (size_t)n, acc);
  int g = batch[n];
  int lane = threadIdx.x & 63;
  float s[DD];
#pragma unroll
  for (int d = 0; d < DD; ++d) s[d] = acc[d];
#pragma unroll
  for (int st = 1; st < 64; st <<= 1) {
    int gu = __shfl_up(g, st, 64);
    bool ok = (lane >= st) && (gu == g);
#pragma unroll
    for (int d = 0; d < DD; ++d) {
      float vu = __shfl_up(s[d], st, 64);
      if (ok) s[d] += vu;
    }
  }
  int gn = __shfl_down(g, 1, 64);
  if ((lane == 63) || (gn != g)) {
#pragma unroll
    for (int d = 0; d < DD; ++d) atomicAdd(&vnsum[(size_t)g * DD + d], s[d]);
  }
}

// Fused: LDS-aggregate fp8-mirror messages; z=(1+eps)h_in+aggr -> X (nt); BN1 stats
__global__ void __launch_bounds__(256)
k_edgeA(const float* __restrict__ hbuf, const uint2* __restrict__ hmA,
        const unsigned char* __restrict__ hmB, const unsigned* __restrict__ binned,
        const int* __restrict__ bucket_base, const float* __restrict__ bond,
        const float* __restrict__ W1l, const float* __restrict__ b1l,
        const float* __restrict__ epsp, float* __restrict__ X,
        float* __restrict__ stats) {
  __shared__ float slice[NPB * DD];   // 18 KB
  __shared__ float comb[8 * DD];
  __shared__ float sW1[DD * HH], sb1[HH], ssum[HH], ssq[HH];
  int tid = threadIdx.x;
  for (int i = tid; i < NPB * DD; i += 256) slice[i] = 0.f;
  for (int i = tid; i < DD * HH; i += 256) sW1[i] = W1l[i];
  if (tid < 8 * DD) {
    int c = tid / DD, d = tid % DD;
    comb[tid] = bond[(0 * 6 + (c & 1)) * DD + d] +
                bond[(1 * 6 + ((c >> 1) & 1)) * DD + d] +
                bond[(2 * 6 + ((c >> 2) & 1)) * DD + d];
  }
  if (tid < HH) { sb1[tid] = b1l[tid]; ssum[tid] = 0.f; ssq[tid] = 0.f; }
  __syncthreads();

  int b = blockIdx.x;
  int start = bucket_base[b];
  int end = bucket_base[b + 1];
  for (int base = start + tid; base < end; base += 1024) {
    unsigned r[4];
    uint2 q[4];
    unsigned char d8[4];
#pragma unroll
    for (int k = 0; k < 4; ++k) {
      int idx = base + k * 256;
      if (idx < end) {
        unsigned rr = __builtin_nontemporal_load(&binned[idx]);
        r[k] = rr;
        unsigned src = rr & 0xFFFFFu;
        q[k] = hmA[src];
        d8[k] = hmB[src];
      }
    }
#pragma unroll
    for (int k = 0; k < 4; ++k) {
      int idx = base + k * 256;
      if (idx < end) {
        float hv[DD] = {f8dec(q[k].x & 255u), f8dec((q[k].x >> 8) & 255u),
                        f8dec((q[k].x >> 16) & 255u), f8dec(q[k].x >> 24),
                        f8dec(q[k].y & 255u), f8dec((q[k].y >> 8) & 255u),
                        f8dec((q[k].y >> 16) & 255u), f8dec(q[k].y >> 24),
                        f8dec((unsigned)d8[k])};
        const float* cb = comb + (r[k] >> 29) * DD;
        float* sl = slice + ((r[k] >> 20) & 511u) * DD;
#pragma unroll
        for (int d = 0; d < DD; ++d) {
          float m = hv[d] + cb[d];
          m = m > 0.f ? m : 0.f;
          atomicAdd(&sl[d], m);
        }
      }
    }
  }
  __syncthreads();

  float eps1 = 1.0f + epsp[0];
  size_t n0 = (size_t)b * NPB;
  float z0[DD], z1[DD];
#pragma unroll
  for (int half = 0; half < 2; ++half) {
    int node = half * 256 + tid;
    size_t n = n0 + node;
    const float* hr = hbuf + n * SB;
    float4 HA = ((const float4*)hr)[0], HB = ((const float4*)hr)[1];
    float h8 = hr[8];
    float hi[DD] = {HA.x, HA.y, HA.z, HA.w, HB.x, HB.y, HB.z, HB.w, h8};
    float* zz = half ? z1 : z0;
#pragma unroll
    for (int d = 0; d < DD; ++d) zz[d] = eps1 * hi[d] + slice[node * DD + d];
    float* xo = X + n * SB;
    fv4 v0 = {zz[0], zz[1], zz[2], zz[3]};
    fv4 v1 = {zz[4], zz[5], zz[6], zz[7]};
    __builtin_nontemporal_store(v0, (fv4*)xo);
    __builtin_nontemporal_store(v1, (fv4*)(xo + 4));
    __builtin_nontemporal_store(zz[8], xo + 8);
  }
  int lane0 = ((tid & 63) == 0);
#pragma unroll
  for (int j = 0; j < HH; ++j) {
    float a0 = sb1[j], a1 = sb1[j];
#pragma unroll
    for (int d = 0; d < DD; ++d) {
      a0 += z0[d] * sW1[d * HH + j];
      a1 += z1[d] * sW1[d * HH + j];
    }
    float rs = waveReduce(a0 + a1);
    float rq = waveReduce(a0 * a0 + a1 * a1);
    if (lane0) { atomicAdd(&ssum[j], rs); atomicAdd(&ssq[j], rq); }
  }
  __syncthreads();
  int copy = (b & 63) * 64;
  if (tid < HH) {
    atomicAdd(&stats[copy + NSUM1 + tid], ssum[tid]);
    atomicAdd(&stats[copy + NSQ1 + tid], ssq[tid]);
  }
}

// in-place X (nt): z2 = relu(bn1(z@W1+b1)) @ W2 + b2;  BN2 stats (spread)
__global__ void __launch_bounds__(256)
k_partB(float* __restrict__ X, const float* __restrict__ W1l, const float* __restrict__ b1l,
        const float* __restrict__ g1, const float* __restrict__ be1,
        const float* __restrict__ W2l, const float* __restrict__ b2l,
        float* __restrict__ stats) {
  __shared__ float sW1[DD * HH], sW2[HH * DD], sb1[HH], sb2[DD];
  __shared__ float sc1[HH], sh1[HH], ssum[DD], ssq[DD];
  int tid = threadIdx.x;
  for (int i = tid; i < DD * HH; i += 256) sW1[i] = W1l[i];
  for (int i = tid; i < HH * DD; i += 256) sW2[i] = W2l[i];
  if (tid < HH) {
    float s = 0.f, q = 0.f;
#pragma unroll
    for (int c = 0; c < 64; ++c) {
      s += stats[c * 64 + NSUM1 + tid];
      q += stats[c * 64 + NSQ1 + tid];
    }
    float mean = s * (1.0f / NN);
    float var = q * (1.0f / NN) - mean * mean;
    float sc = g1[tid] * rsqrtf(var + BN_EPS);
    sc1[tid] = sc;
    sh1[tid] = be1[tid] - mean * sc;
    sb1[tid] = b1l[tid];
  }
  if (tid < DD) { sb2[tid] = b2l[tid]; ssum[tid] = 0.f; ssq[tid] = 0.f; }
  __syncthreads();
  size_t n = (size_t)blockIdx.x * 256 + tid;
  float* xr = X + n * SB;
  fv4 XA = __builtin_nontemporal_load((const fv4*)xr);
  fv4 XB = __builtin_nontemporal_load((const fv4*)(xr + 4));
  float x8 = __builtin_nontemporal_load(xr + 8);
  float z[DD] = {XA.x, XA.y, XA.z, XA.w, XB.x, XB.y, XB.z, XB.w, x8};
  float t[HH];
#pragma unroll
  for (int j = 0; j < HH; ++j) {
    float a = sb1[j];
#pragma unroll
    for (int d = 0; d < DD; ++d) a += z[d] * sW1[d * HH + j];
    a = a * sc1[j] + sh1[j];
    t[j] = a > 0.f ? a : 0.f;
  }
  float z2[DD];
  int lane0 = ((tid & 63) == 0);
#pragma unroll
  for (int d = 0; d < DD; ++d) {
    float a = sb2[d];
#pragma unroll
    for (int j = 0; j < HH; ++j) a += t[j] * sW2[j * DD + d];
    z2[d] = a;
    float rs = waveReduce(a);
    float rq = waveReduce(a * a);
    if (lane0) { atomicAdd(&ssum[d], rs); atomicAdd(&ssq[d], rq); }
  }
  fv4 v0 = {z2[0], z2[1], z2[2], z2[3]};
  fv4 v1 = {z2[4], z2[5], z2[6], z2[7]};
  __builtin_nontemporal_store(v0, (fv4*)xr);
  __builtin_nontemporal_store(v1, (fv4*)(xr + 4));
  __builtin_nontemporal_store(z2[8], xr + 8);
  __syncthreads();
  int copy = ((int)blockIdx.x & 63) * 64;
  if (tid < DD) {
    atomicAdd(&stats[copy + NSUM2 + tid], ssum[tid]);
    atomicAdd(&stats[copy + NSQ2 + tid], ssq[tid]);
  }
}

// h_new = bn2(z2)[relu] + h_in; vn add + mirrors; last layer: spread out-sums
__global__ void __launch_bounds__(256)
k_partC(const float* __restrict__ X, float* __restrict__ hbuf,
        uint2* __restrict__ hmA, unsigned char* __restrict__ hmB,
        float* __restrict__ stats, const float* __restrict__ g2,
        const float* __restrict__ be2, const int* __restrict__ batch,
        const float* __restrict__ vn_next, float* __restrict__ vnsum_out,
        int do_relu) {
  __shared__ float sc[DD], sh[DD], ssum[DD];
  int tid = threadIdx.x;
  if (tid < DD) {
    float s = 0.f, q = 0.f;
#pragma unroll
    for (int c = 0; c < 64; ++c) {
      s += stats[c * 64 + NSUM2 + tid];
      q += stats[c * 64 + NSQ2 + tid];
    }
    float mean = s * (1.0f / NN);
    float var = q * (1.0f / NN) - mean * mean;
    float sg = g2[tid] * rsqrtf(var + BN_EPS);
    sc[tid] = sg;
    sh[tid] = be2[tid] - mean * sg;
    ssum[tid] = 0.f;
  }
  __syncthreads();
  size_t n = (size_t)blockIdx.x * 256 + tid;
  const float* xr = X + n * SB;
  fv4 XA = __builtin_nontemporal_load((const fv4*)xr);
  fv4 XB = __builtin_nontemporal_load((const fv4*)(xr + 4));
  float x8 = __builtin_nontemporal_load(xr + 8);
  float zv[DD] = {XA.x, XA.y, XA.z, XA.w, XB.x, XB.y, XB.z, XB.w, x8};
  float* hr = hbuf + n * SB;
  float4 HA = ((float4*)hr)[0], HB = ((float4*)hr)[1];
  float h8 = hr[8];
  float hi[DD] = {HA.x, HA.y, HA.z, HA.w, HB.x, HB.y, HB.z, HB.w, h8};
  float hv[DD];
#pragma unroll
  for (int d = 0; d < DD; ++d) {
    float z = zv[d] * sc[d] + sh[d];
    if (do_relu) z = z > 0.f ? z : 0.f;
    hv[d] = z + hi[d];
  }
  if (vn_next != nullptr) {
    int g = batch[n];
#pragma unroll
    for (int d = 0; d < DD; ++d) hv[d] += vn_next[(size_t)g * DD + d];
    ((float4*)hr)[0] = make_float4(hv[0], hv[1], hv[2], hv[3]);
    ((float4*)hr)[1] = make_float4(hv[4], hv[5], hv[6], hv[7]);
    hr[8] = hv[8];
    writeMirror(hmA, hmB, n, hv);
    if (vnsum_out != nullptr) {
      int lane = tid & 63;
      float s[DD];
#pragma unroll
      for (int d = 0; d < DD; ++d) s[d] = hv[d];
#pragma unroll
      for (int st = 1; st < 64; st <<= 1) {
        int gu = __shfl_up(g, st, 64);
        bool ok = (lane >= st) && (gu == g);
#pragma unroll
        for (int d = 0; d < DD; ++d) {
          float vu = __shfl_up(s[d], st, 64);
          if (ok) s[d] += vu;
        }
      }
      int gn = __shfl_down(g, 1, 64);
      if ((lane == 63) || (gn != g)) {
#pragma unroll
        for (int d = 0; d < DD; ++d) atomicAdd(&vnsum_out[(size_t)g * DD + d], s[d]);
      }
    }
  } else {
    int lane0 = ((tid & 63) == 0);
#pragma unroll
    for (int d = 0; d < DD; ++d) {
      float r = waveReduce(hv[d]);
      if (lane0) atomicAdd(&ssum[d], r);
    }
    __syncthreads();
    int copy = ((int)blockIdx.x & 63) * 64;
    if (tid < DD) atomicAdd(&stats[copy + OUTS + tid], ssum[tid]);
  }
}

// reduce spread out-sums -> d_out
__global__ void k_out(const float* __restrict__ stats, float* __restrict__ out) {
  int tid = threadIdx.x;
  if (tid < DD) {
    float s = 0.f;
#pragma unroll
    for (int c = 0; c < 64; ++c) s += stats[c * 64 + OUTS + tid];
    out[tid] = s;
  }
}

// ---------------- virtual-node MLP ----------------

__global__ void k_vnA(const float* __restrict__ vnsum, const float* __restrict__ vn,
                      float* __restrict__ vt1, const float* __restrict__ W1l,
                      const float* __restrict__ b1l, float* __restrict__ stats) {
  __shared__ float sW[DD * HH], sb[HH], ssum[HH], ssq[HH];
  int tid = threadIdx.x;
  for (int i = tid; i < DD * HH; i += 256) sW[i] = W1l[i];
  if (tid < HH) { sb[tid] = b1l[tid]; ssum[tid] = 0.f; ssq[tid] = 0.f; }
  __syncthreads();
  size_t g = (size_t)blockIdx.x * 256 + tid;
  float r[DD];
#pragma unroll
  for (int d = 0; d < DD; ++d) r[d] = vnsum[g * DD + d] + vn[g * DD + d];
  int lane0 = ((tid & 63) == 0);
#pragma unroll
  for (int j = 0; j < HH; ++j) {
    float a = sb[j];
#pragma unroll
    for (int d = 0; d < DD; ++d) a += r[d] * sW[d * HH + j];
    vt1[g * HH + j] = a;
    float rs = waveReduce(a);
    float rq = waveReduce(a * a);
    if (lane0) { atomicAdd(&ssum[j], rs); atomicAdd(&ssq[j], rq); }
  }
  __syncthreads();
  if (tid < HH) {
    atomicAdd(&stats[VSUM1 + tid], ssum[tid]);
    atomicAdd(&stats[VSQ1 + tid], ssq[tid]);
  }
}

__global__ void k_vnB(const float* __restrict__ vt1, float* __restrict__ vt2,
                      const float* __restrict__ W2l, const float* __restrict__ b2l,
                      const float* __restrict__ g1, const float* __restrict__ be1,
                      float* __restrict__ stats) {
  __shared__ float sW2[HH * DD], sb2[DD], sc1[HH], sh1[HH], ssum[DD], ssq[DD];
  int tid = threadIdx.x;
  for (int i = tid; i < HH * DD; i += 256) sW2[i] = W2l[i];
  if (tid < HH) {
    float mean = stats[VSUM1 + tid] * (1.0f / NG);
    float var = stats[VSQ1 + tid] * (1.0f / NG) - mean * mean;
    float sc = g1[tid] * rsqrtf(var + BN_EPS);
    sc1[tid] = sc;
    sh1[tid] = be1[tid] - mean * sc;
  }
  if (tid < DD) { sb2[tid] = b2l[tid]; ssum[tid] = 0.f; ssq[tid] = 0.f; }
  __syncthreads();
  size_t g = (size_t)blockIdx.x * 256 + tid;
  float t[HH];
#pragma unroll
  for (int j = 0; j < HH; ++j) {
    float a = vt1[g * HH + j] * sc1[j] + sh1[j];
    t[j] = a > 0.f ? a : 0.f;
  }
  int lane0 = ((tid & 63) == 0);
#pragma unroll
  for (int d = 0; d < DD; ++d) {
    float a = sb2[d];
#pragma unroll
    for (int j = 0; j < HH; ++j) a += t[j] * sW2[j * DD + d];
    vt2[g * DD + d] = a;
    float rs = waveReduce(a);
    float rq = waveReduce(a * a);
    if (lane0) { atomicAdd(&ssum[d], rs); atomicAdd(&ssq[d], rq); }
  }
  __syncthreads();
  if (tid < DD) {
    atomicAdd(&stats[VSUM2 + tid], ssum[tid]);
    atomicAdd(&stats[VSQ2 + tid], ssq[tid]);
  }
}

__global__ void k_vnC(const float* __restrict__ vt2, float* __restrict__ vn,
                      const float* __restrict__ g2, const float* __restrict__ be2,
                      const float* __restrict__ stats) {
  __shared__ float sc[DD], sh[DD];
  int tid = threadIdx.x;
  if (tid < DD) {
    float mean = stats[VSUM2 + tid] * (1.0f / NG);
    float var = stats[VSQ2 + tid] * (1.0f / NG) - mean * mean;
    float s = g2[tid] * rsqrtf(var + BN_EPS);
    sc[tid] = s;
    sh[tid] = be2[tid] - mean * s;
  }
  __syncthreads();
  size_t g = (size_t)blockIdx.x * 256 + tid;
#pragma unroll
  for (int d = 0; d < DD; ++d) {
    float v = vt2[g * DD + d] * sc[d] + sh[d];
    v = v > 0.f ? v : 0.f;
    vn[g * DD + d] += v;
  }
}

extern "C" void kernel_launch(void* const* d_in, const int* in_sizes, int n_in,
                              void* d_out, int out_size, void* d_ws, size_t ws_size,
                              hipStream_t stream) {
  const float* atom_emb = (const float*)d_in[0];
  const float* bond_emb = (const float*)d_in[1];
  const float* eps_gin  = (const float*)d_in[2];
  const float* W1   = (const float*)d_in[3];
  const float* b1   = (const float*)d_in[4];
  const float* bn1_g = (const float*)d_in[5];
  const float* bn1_b = (const float*)d_in[6];
  const float* W2   = (const float*)d_in[7];
  const float* b2   = (const float*)d_in[8];
  const float* bno_g = (const float*)d_in[9];
  const float* bno_b = (const float*)d_in[10];
  const float* vnW1 = (const float*)d_in[11];
  const float* vnb1 = (const float*)d_in[12];
  const float* vnbn1_g = (const float*)d_in[13];
  const float* vnbn1_b = (const float*)d_in[14];
  const float* vnW2 = (const float*)d_in[15];
  const float* vnb2 = (const float*)d_in[16];
  const float* vnbn2_g = (const float*)d_in[17];
  const float* vnbn2_b = (const float*)d_in[18];
  const int* x          = (const int*)d_in[19];
  const int* edge_index = (const int*)d_in[20];
  const int* edge_attr  = (const int*)d_in[21];
  const int* batch      = (const int*)d_in[22];
  float* out = (float*)d_out;

  // workspace layout (floats) — ~140 MB
  float* hbuf  = (float*)d_ws;                          // NN*SB (48 MB)
  float* X     = hbuf + (size_t)NN * SB;                // NN*SB (48 MB)
  uint2* hmA   = (uint2*)(X + (size_t)NN * SB);         // NN uint2 (8 MB)
  unsigned char* hmB = (unsigned char*)(hmA + (size_t)NN);  // NN bytes (1 MB)
  unsigned* binned = (unsigned*)(hmB + (size_t)NN);     // NE u32 (33.5 MB)
  uint2* coarse = (uint2*)d_ws;                         // overlays hbuf+X (dead until k_atom)
  float* vn    = (float*)(binned + (size_t)NE);         // NG*DD
  float* vnsum = vn + (size_t)NG * DD;                  // NG*DD (vt2 overlays)
  float* vt2   = vnsum;
  float* vt1   = vnsum + (size_t)NG * DD;               // NG*HH
  float* stats = vt1 + (size_t)NG * HH;                 // STATS_FLOATS
  int* bucket_count  = (int*)(stats + STATS_FLOATS);    // NB
  int* bucket_base   = bucket_count + NB;               // NB+1
  int* bucket_cursor = bucket_base + NB + 1;            // NB
  int* group_cursor  = bucket_cursor + NB;              // NGRP*16

  // ---- one-time binning ----
  (void)hipMemsetAsync(bucket_count, 0, NB * sizeof(int), stream);
  k_count<<<2048, 256, 0, stream>>>(edge_index, bucket_count);
  k_scan<<<1, 256, 0, stream>>>(bucket_count, bucket_base, bucket_cursor, group_cursor);
  k_p1<<<512, 256, 0, stream>>>(edge_index, edge_attr, group_cursor, coarse);
  k_p2<<<NGRP * 8, 256, 0, stream>>>(coarse, bucket_base, bucket_cursor, binned);

  (void)hipMemsetAsync(vn, 0, (size_t)2 * NG * DD * sizeof(float), stream);
  k_atom<<<NN / 256, 256, 0, stream>>>(atom_emb, x, batch, hbuf, hmA, hmB, vnsum);

  for (int l = 0; l < 3; ++l) {
    int has_vn = (l < 2);
    (void)hipMemsetAsync(stats, 0, STATS_FLOATS * sizeof(float), stream);
    if (has_vn) {
      k_vnA<<<NG / 256, 256, 0, stream>>>(vnsum, vn, vt1, vnW1 + (size_t)l * DD * HH,
                                          vnb1 + (size_t)l * HH, stats);
      k_vnB<<<NG / 256, 256, 0, stream>>>(vt1, vt2, vnW2 + (size_t)l * HH * DD,
                                          vnb2 + (size_t)l * DD,
                                          vnbn1_g + (size_t)l * HH, vnbn1_b + (size_t)l * HH,
                                          stats);
      k_vnC<<<NG / 256, 256, 0, stream>>>(vt2, vn, vnbn2_g + (size_t)l * DD,
                                          vnbn2_b + (size_t)l * DD, stats);
    }
    k_edgeA<<<NB, 256, 0, stream>>>(hbuf, hmA, hmB, binned, bucket_base,
                                    bond_emb + (size_t)l * 3 * 6 * DD,
                                    W1 + (size_t)l * DD * HH, b1 + (size_t)l * HH,
                                    eps_gin + l, X, stats);
    k_partB<<<NN / 256, 256, 0, stream>>>(X, W1 + (size_t)l * DD * HH,
                                          b1 + (size_t)l * HH,
                                          bn1_g + (size_t)l * HH, bn1_b + (size_t)l * HH,
                                          W2 + (size_t)l * HH * DD, b2 + (size_t)l * DD,
                                          stats);
    if (l == 0)
      (void)hipMemsetAsync(vnsum, 0, (size_t)NG * DD * sizeof(float), stream);
    k_partC<<<NN / 256, 256, 0, stream>>>(X, hbuf, hmA, hmB, stats,
                                          bno_g + (size_t)l * DD, bno_b + (size_t)l * DD,
                                          batch,
                                          has_vn ? vn : nullptr,
                                          (l == 0) ? vnsum : nullptr,
                                          has_vn ? 1 : 0);
  }
  k_out<<<1, 64, 0, stream>>>(stats, out);
}